// Round 13
// baseline (1231.695 us; speedup 1.0000x reference)
//
#include <hip/hip_runtime.h>
#include <math.h>

#define PX 4096         // 64*64 spatial
#define EPS 1e-5f

typedef __attribute__((ext_vector_type(8))) __bf16 bf16x8;
typedef __attribute__((ext_vector_type(4))) float f32x4;

static __device__ __forceinline__ unsigned short f2b(float f) {
    unsigned int u = __float_as_uint(f);
    u += 0x7FFFu + ((u >> 16) & 1u);     // RTNE
    return (unsigned short)(u >> 16);
}
static __device__ __forceinline__ float b2f(unsigned short u) {
    return __uint_as_float((unsigned int)u << 16);
}
static __device__ __forceinline__ float rcpf(float x) {
    return __builtin_amdgcn_rcpf(x);
}

// ---------------------------------------------------------------------------
// ws layout (float units):
//   comb_t  bf16 [64 n][4096 px][128 ic]          16,777,216 f  @ 0
//   gatesb  bf16 [8 dirb][256 oc][4096 px]         4,194,304 f  @ 16,777,216
//   cbuf    bf16 [8 dirb][64 ch][4096]             1,048,576 f  @ 20,971,520
//   gnstat  f32  [16 s][2 dir][4 b][4 g][2]            1,024 f  @ 23,068,672
//   bnparts f32  [8 part][64 oc][2]                    1,024 f  @ 23,069,696
//   W3      bf16 [dir][ocblk][icblk][tap][mi][64 l][8 j] 294,912 f @ 23,070,720
//   wfrag   bf16 [4 ocb][4 icblk][64 l][8 j]           4,096 f  @ 23,365,632
//   xb      bf16 [64 bt][4096 px][64 ic]            8,388,608 f @ 23,369,728
//
// R13 conv: weights via register-rotated global fragments (read ONCE per
// block -> no LDS residency), input via single 21.8KB LDS buffer (read 9x ->
// LDS is right for it). LDS 58.9->22KB unlocks 4 blocks/CU (16 waves/CU,
// launch_bounds(256,4)) to hide the load latency that capped R5/R9 at 2
// blocks/CU. XCD-local 1-D grid (dirb=blockIdx&7) throughout; c in bf16.
// ---------------------------------------------------------------------------

// Pack conv weights bf16 directly in per-lane MFMA A-fragment order.
__global__ __launch_bounds__(256) void wconv3_kernel(
    const float* __restrict__ Wf, const float* __restrict__ Wb,
    unsigned short* __restrict__ W3)
{
    int idx = blockIdx.x * 256 + threadIdx.x;
    if (idx >= 589824) return;
    int j = idx & 7;
    int l = (idx >> 3) & 63;
    int mi = (idx >> 9) & 3;
    int g = idx >> 11;            // ((dir*4+ocblk)*4+icblk)*9 + tap
    int tap = g % 9;
    int gg = g / 9;
    int icblk = gg & 3;
    int ocblk = (gg >> 2) & 3;
    int dir = gg >> 4;
    int oc = ocblk * 64 + mi * 16 + (l & 15);
    int ic = icblk * 32 + (l >> 4) * 8 + j;
    const float* __restrict__ W = dir ? Wb : Wf;
    W3[idx] = f2b(W[((size_t)oc * 128 + ic) * 9 + tap]);
}

// Pack Wfu into MFMA B-fragment order: [ocb][icblk][lane][j]
__global__ __launch_bounds__(256) void wfu_pack_kernel(
    const float* __restrict__ Wfu, unsigned short* __restrict__ wfrag)
{
    int idx = blockIdx.x * 256 + threadIdx.x;
    if (idx >= 8192) return;
    int j = idx & 7;
    int l = (idx >> 3) & 63;
    int icblk = (idx >> 9) & 3;
    int ocb = idx >> 11;
    int oc = ocb * 16 + (l & 15);
    int ic = icblk * 32 + (l >> 4) * 8 + j;
    wfrag[idx] = f2b(Wfu[oc * 128 + ic]);
}

// Transpose x to px-major bf16: xb[bt][px][64 ic].
__global__ __launch_bounds__(256) void xconv_kernel(
    const float* __restrict__ x, unsigned short* __restrict__ xb)
{
    int bt = blockIdx.x >> 6;
    int px0 = (blockIdx.x & 63) * 64;
    __shared__ unsigned short sh[64 * 72];
    int tid = threadIdx.x;
    {
        int px_l = tid & 63;
        int ic4 = tid >> 6;
        const float* __restrict__ src = x + (size_t)bt * 64 * PX + px0 + px_l;
#pragma unroll
        for (int k = 0; k < 16; ++k) {
            int ic = ic4 * 16 + k;
            sh[px_l * 72 + ic] = f2b(src[(size_t)ic * PX]);
        }
    }
    __syncthreads();
    {
        int px_w = tid >> 2;
        int ch = tid & 3;
        uint4 v0 = *reinterpret_cast<const uint4*>(&sh[px_w * 72 + ch * 16]);
        uint4 v1 = *reinterpret_cast<const uint4*>(&sh[px_w * 72 + ch * 16 + 8]);
        unsigned short* dst = xb + ((size_t)bt * PX + px0 + px_w) * 64 + ch * 16;
        *reinterpret_cast<uint4*>(dst) = v0;
        *reinterpret_cast<uint4*>(dst + 8) = v1;
    }
}

// K1: implicit-GEMM conv via MFMA.
// Weights: global->register fragments, 2-deep rotating prefetch (per-lane
// packed, read once per block). Input: single-buffer LDS halo tile.
// grid 512 (1-D): dirb = blockIdx&7 (XCD-local); rest: ocblk(4) x pxt(16).
__global__ __launch_bounds__(256, 4) void conv_mfma_kernel(
    const unsigned short* __restrict__ xb, const unsigned short* __restrict__ comb_t,
    const unsigned short* __restrict__ W3,
    unsigned short* __restrict__ gatesb, float* __restrict__ gnstats, int s)
{
    const int dirb = blockIdx.x & 7;
    const int rest = blockIdx.x >> 3;
    const int dir = dirb >> 2, b = dirb & 3;
    const int ocblk = rest >> 4;
    const int pxt = rest & 15;
    const int py0 = (pxt >> 1) * 8;
    const int pxc0 = (pxt & 1) * 32;
    const int t = dir ? (15 - s) : s;
    const int prev_t = dir ? (t + 1) : (t - 1);

    __shared__ __align__(16) unsigned short in_s[340 * 32];    // 21,760 B
    __shared__ float red[8];

    const int tid = threadIdx.x;
    const int w = tid >> 6;
    const int l = tid & 63;
    const int l15 = l & 15;
    const int l4 = l >> 4;

    const unsigned short* __restrict__ xpx = xb + (size_t)(b * 16 + t) * PX * 64;
    const unsigned short* __restrict__ hpx = comb_t
        + (size_t)(prev_t * 4 + b) * PX * 128 + dir * 64;
    const unsigned short* __restrict__ wbase = W3
        + (size_t)(dir * 4 + ocblk) * 36 * 2048 + l * 8;

    // staging address precompute (per-lane, reused each phase)
    int sg_px[6];      // global pixel index, -1 if out of tile
#pragma unroll
    for (int it = 0; it < 6; ++it) {
        int idx = tid + it * 256;
        int pl = idx >> 2;
        int row = (pl * 241) >> 13;          // pl / 34
        int col = pl - row * 34;
        int gy = py0 - 1 + row;
        int gx = pxc0 - 1 + col;
        bool valid = (idx < 1360) && ((unsigned)gy < 64u) && ((unsigned)gx < 64u);
        sg_px[it] = valid ? (gy * 64 + gx) : -1;
    }

    f32x4 acc[4][4];
#pragma unroll
    for (int i = 0; i < 4; ++i)
#pragma unroll
        for (int j = 0; j < 4; ++j)
            acc[i][j] = (f32x4){0.f, 0.f, 0.f, 0.f};

    // direct staging: load uint4 -> ds_write (latency hidden by 16 waves/CU)
    auto stage = [&](int icblk) {
        const bool useh = icblk >= 2;
        const unsigned short* __restrict__ srcpx = useh
            ? (hpx + (icblk - 2) * 32) : (xpx + icblk * 32);
        const int rec = useh ? 128 : 64;
        const bool zero = useh && (s == 0);
        const int c = tid & 3;
#pragma unroll
        for (int it = 0; it < 6; ++it) {
            int idx = tid + it * 256;
            if (idx < 1360) {
                int pl = idx >> 2;
                uint4 v = make_uint4(0u, 0u, 0u, 0u);
                if (sg_px[it] >= 0 && !zero)
                    v = *reinterpret_cast<const uint4*>(
                        srcpx + (size_t)sg_px[it] * rec + c * 8);
                int woff = pl * 32 + ((c ^ ((pl >> 1) & 3)) * 8);
                *reinterpret_cast<uint4*>(&in_s[woff]) = v;
            }
        }
    };

    bf16x8 av[2][4];
    auto loadW = [&](int slot, int g) {
#pragma unroll
        for (int mi = 0; mi < 4; ++mi)
            av[slot][mi] = *reinterpret_cast<const bf16x8*>(
                wbase + (size_t)(g * 4 + mi) * 512);
    };

    loadW(0, 0);

    for (int icblk = 0; icblk < 4; ++icblk) {
        __syncthreads();                 // prior compute done reading in_s
        stage(icblk);
        __syncthreads();                 // in_s ready

#pragma unroll
        for (int tap = 0; tap < 9; ++tap) {
            const int g = icblk * 9 + tap;
            if (g < 35) loadW((g + 1) & 1, g + 1);     // prefetch next frag
            const int dy = tap / 3, dx = tap % 3;
            bf16x8 bv[4];
#pragma unroll
            for (int ni = 0; ni < 4; ++ni) {
                int nr = ni >> 1, nc = ni & 1;
                int pl = (2 * w + nr + dy) * 34 + nc * 16 + l15 + dx;
                int boff = pl * 32 + ((l4 ^ ((pl >> 1) & 3)) * 8);
                bv[ni] = *reinterpret_cast<const bf16x8*>(&in_s[boff]);
            }
#pragma unroll
            for (int mi = 0; mi < 4; ++mi)
#pragma unroll
                for (int ni = 0; ni < 4; ++ni)
                    acc[mi][ni] = __builtin_amdgcn_mfma_f32_16x16x32_bf16(
                        av[g & 1][mi], bv[ni], acc[mi][ni], 0, 0, 0);
        }
    }

    // epilogue: write gates (bf16) + GN partial stats (fp32 from acc)
    float s1 = 0.f, s2 = 0.f;
    unsigned short* __restrict__ gbase = gatesb
        + ((size_t)dirb * 256 + (size_t)ocblk * 64) * PX;
#pragma unroll
    for (int mi = 0; mi < 4; ++mi)
#pragma unroll
        for (int ni = 0; ni < 4; ++ni) {
            int nr = ni >> 1, nc = ni & 1;
            int px = (py0 + 2 * w + nr) * 64 + pxc0 + nc * 16 + l15;
#pragma unroll
            for (int j = 0; j < 4; ++j) {
                float v = acc[mi][ni][j];
                int oc = mi * 16 + l4 * 4 + j;
                gbase[(size_t)oc * PX + px] = f2b(v);
                s1 += v;
                s2 += v * v;
            }
        }
    for (int off = 32; off; off >>= 1) {
        s1 += __shfl_down(s1, off);
        s2 += __shfl_down(s2, off);
    }
    if (l == 0) { red[w * 2] = s1; red[w * 2 + 1] = s2; }
    __syncthreads();
    if (tid == 0) {
        float a = red[0] + red[2] + red[4] + red[6];
        float q = red[1] + red[3] + red[5] + red[7];
        float* slot = gnstats + (((size_t)(s * 2 + dir) * 4 + b) * 4 + ocblk) * 2;
        atomicAdd(slot, a);
        atomicAdd(slot + 1, q);
    }
}

// K2: GN + activations + LSTM update; c stored bf16; h -> comb_t (bf16).
// grid 1024 (1-D): dirb = blockIdx&7 (XCD-local, same mapping as conv).
__global__ __launch_bounds__(256) void point_kernel2(
    const unsigned short* __restrict__ gatesb, const float* __restrict__ gnstats,
    const float* __restrict__ gnf_w, const float* __restrict__ gnf_b,
    const float* __restrict__ gnb_w, const float* __restrict__ gnb_b,
    unsigned short* __restrict__ cbuf, unsigned short* __restrict__ comb_t, int s)
{
    int dirb = blockIdx.x & 7;
    int idx = (blockIdx.x >> 3) * 256 + threadIdx.x;   // 0..32767 within dirb
    int pxl = idx & 7;
    int o8 = (idx >> 3) & 7;
    int pxh = idx >> 6;                                // 0..511
    int px = pxh * 8 + pxl;
    int dir = dirb >> 2, b = dirb & 3;

    __shared__ float gwl[256], gbl[256], mrs[8];
    int tid = threadIdx.x;
    {
        const float* __restrict__ gw = dir ? gnb_w : gnf_w;
        const float* __restrict__ gb = dir ? gnb_b : gnf_b;
        gwl[tid] = gw[tid];
        gbl[tid] = gb[tid];
    }
    if (tid < 4) {
        const float* slot = gnstats + ((size_t)(s * 2 + dir) * 4 + b) * 8 + tid * 2;
        const float invN = 1.0f / 262144.0f;
        float mean = slot[0] * invN;
        float var = slot[1] * invN - mean * mean;
        mrs[tid * 2] = mean;
        mrs[tid * 2 + 1] = rsqrtf(var + EPS);
    }
    __syncthreads();

    const unsigned short* __restrict__ gbase = gatesb + (size_t)dirb * 256 * PX + px;
    size_t cbase = ((size_t)dirb * 64 + o8 * 8) * PX + px;
    float m0 = mrs[0], r0 = mrs[1], m1 = mrs[2], r1 = mrs[3];
    float m2 = mrs[4], r2 = mrs[5], m3 = mrs[6], r3 = mrs[7];

    unsigned int packed[4];
#pragma unroll
    for (int cc = 0; cc < 8; ++cc) {
        int ch = o8 * 8 + cc;
        float g0 = b2f(gbase[(size_t)(ch) * PX]);
        float g1 = b2f(gbase[(size_t)(64 + ch) * PX]);
        float g2 = b2f(gbase[(size_t)(128 + ch) * PX]);
        float g3 = b2f(gbase[(size_t)(192 + ch) * PX]);
        float v0 = (g0 - m0) * r0 * gwl[ch] + gbl[ch];
        float v1 = (g1 - m1) * r1 * gwl[64 + ch] + gbl[64 + ch];
        float v2 = (g2 - m2) * r2 * gwl[128 + ch] + gbl[128 + ch];
        float v3 = (g3 - m3) * r3 * gwl[192 + ch] + gbl[192 + ch];
        float ig = rcpf(1.f + __expf(-v0));
        float fg = rcpf(1.f + __expf(-v1));
        float og = rcpf(1.f + __expf(-v2));
        float gg = 1.f - 2.f * rcpf(1.f + __expf(2.f * v3));
        float cold = b2f(cbuf[cbase + (size_t)cc * PX]);
        float cnew = fg * cold + ig * gg;
        float th = 1.f - 2.f * rcpf(1.f + __expf(2.f * cnew));
        float hnew = og * th;
        cbuf[cbase + (size_t)cc * PX] = f2b(cnew);
        unsigned int hb = (unsigned int)f2b(hnew);
        if (cc & 1) packed[cc >> 1] |= hb << 16;
        else        packed[cc >> 1] = hb;
    }
    int t = dir ? (15 - s) : s;
    size_t co = ((size_t)(t * 4 + b) * PX + px) * 128 + dir * 64 + o8 * 8;
    *reinterpret_cast<uint4*>(comb_t + co) =
        make_uint4(packed[0], packed[1], packed[2], packed[3]);
}

// K3: 1x1 fuse conv via MFMA; BN partial stats only.
__global__ __launch_bounds__(256) void fuse_stats2_kernel(
    const unsigned short* __restrict__ comb_t,
    const unsigned short* __restrict__ wfrag, float* __restrict__ bnparts)
{
    int n = blockIdx.x >> 4, pxb = blockIdx.x & 15;
    int tid = threadIdx.x;
    int w = tid >> 6, l = tid & 63;
    int l15 = l & 15, l4 = l >> 4;

    bf16x8 B[4][4];
#pragma unroll
    for (int ocb = 0; ocb < 4; ++ocb)
#pragma unroll
        for (int icblk = 0; icblk < 4; ++icblk)
            B[ocb][icblk] = *reinterpret_cast<const bf16x8*>(
                wfrag + (((ocb * 4 + icblk) * 64 + l) * 8));

    f32x4 acc[4][4];
#pragma unroll
    for (int i = 0; i < 4; ++i)
#pragma unroll
        for (int j = 0; j < 4; ++j)
            acc[i][j] = (f32x4){0.f, 0.f, 0.f, 0.f};

    int px0 = pxb * 256 + w * 64;
    const unsigned short* __restrict__ cb = comb_t + (size_t)n * PX * 128;
#pragma unroll
    for (int ps = 0; ps < 4; ++ps) {
        const unsigned short* ab = cb + (size_t)(px0 + ps * 16 + l15) * 128 + l4 * 8;
        bf16x8 A[4];
#pragma unroll
        for (int icblk = 0; icblk < 4; ++icblk)
            A[icblk] = *reinterpret_cast<const bf16x8*>(ab + icblk * 32);
#pragma unroll
        for (int icblk = 0; icblk < 4; ++icblk)
#pragma unroll
            for (int ocb = 0; ocb < 4; ++ocb)
                acc[ps][ocb] = __builtin_amdgcn_mfma_f32_16x16x32_bf16(
                    A[icblk], B[ocb][icblk], acc[ps][ocb], 0, 0, 0);
    }

    float s1[4] = {0, 0, 0, 0}, s2[4] = {0, 0, 0, 0};
#pragma unroll
    for (int ps = 0; ps < 4; ++ps)
#pragma unroll
        for (int ocb = 0; ocb < 4; ++ocb)
#pragma unroll
            for (int j = 0; j < 4; ++j) {
                float v = acc[ps][ocb][j];
                s1[ocb] += v;
                s2[ocb] += v * v;
            }
#pragma unroll
    for (int ocb = 0; ocb < 4; ++ocb) {
        s1[ocb] += __shfl_down(s1[ocb], 32);
        s1[ocb] += __shfl_down(s1[ocb], 16);
        s2[ocb] += __shfl_down(s2[ocb], 32);
        s2[ocb] += __shfl_down(s2[ocb], 16);
    }
    __shared__ float sred[4][4][16][2];
    if (l < 16)
#pragma unroll
        for (int ocb = 0; ocb < 4; ++ocb) {
            sred[w][ocb][l][0] = s1[ocb];
            sred[w][ocb][l][1] = s2[ocb];
        }
    __syncthreads();
    if (tid < 128) {
        int oc = tid >> 1, isq = tid & 1;
        float v = sred[0][oc >> 4][oc & 15][isq] + sred[1][oc >> 4][oc & 15][isq]
                + sred[2][oc >> 4][oc & 15][isq] + sred[3][oc >> 4][oc & 15][isq];
        atomicAdd(bnparts + (blockIdx.x & 7) * 128 + tid, v);
    }
}

// K4: recompute fuse MFMA, BN + ReLU, transposed store to out.
__global__ __launch_bounds__(256) void bn_apply2_kernel(
    const unsigned short* __restrict__ comb_t,
    const unsigned short* __restrict__ wfrag, const float* __restrict__ bnparts,
    const float* __restrict__ bn_w, const float* __restrict__ bn_b,
    float* __restrict__ out)
{
    int n = blockIdx.x >> 4, pxb = blockIdx.x & 15;
    int tid = threadIdx.x;
    int w = tid >> 6, l = tid & 63;
    int l15 = l & 15, l4 = l >> 4;

    __shared__ float sc[64], sh[64];
    if (tid < 64) {
        const float invN = 1.0f / 262144.0f;
        float S = 0.f, Q = 0.f;
#pragma unroll
        for (int p = 0; p < 8; ++p) {
            S += bnparts[p * 128 + tid * 2];
            Q += bnparts[p * 128 + tid * 2 + 1];
        }
        float mean = S * invN;
        float var = Q * invN - mean * mean;
        float scale = rsqrtf(var + EPS) * bn_w[tid];
        sc[tid] = scale;
        sh[tid] = bn_b[tid] - mean * scale;
    }

    bf16x8 B[4][4];
#pragma unroll
    for (int ocb = 0; ocb < 4; ++ocb)
#pragma unroll
        for (int icblk = 0; icblk < 4; ++icblk)
            B[ocb][icblk] = *reinterpret_cast<const bf16x8*>(
                wfrag + (((ocb * 4 + icblk) * 64 + l) * 8));
    __syncthreads();

    f32x4 acc[4][4];
#pragma unroll
    for (int i = 0; i < 4; ++i)
#pragma unroll
        for (int j = 0; j < 4; ++j)
            acc[i][j] = (f32x4){0.f, 0.f, 0.f, 0.f};

    int px0 = pxb * 256 + w * 64;
    const unsigned short* __restrict__ cb = comb_t + (size_t)n * PX * 128;
#pragma unroll
    for (int ps = 0; ps < 4; ++ps) {
        const unsigned short* ab = cb + (size_t)(px0 + ps * 16 + l15) * 128 + l4 * 8;
        bf16x8 A[4];
#pragma unroll
        for (int icblk = 0; icblk < 4; ++icblk)
            A[icblk] = *reinterpret_cast<const bf16x8*>(ab + icblk * 32);
#pragma unroll
        for (int icblk = 0; icblk < 4; ++icblk)
#pragma unroll
            for (int ocb = 0; ocb < 4; ++ocb)
                acc[ps][ocb] = __builtin_amdgcn_mfma_f32_16x16x32_bf16(
                    A[icblk], B[ocb][icblk], acc[ps][ocb], 0, 0, 0);
    }

    int t = n >> 2, bb = n & 3;
#pragma unroll
    for (int ps = 0; ps < 4; ++ps)
#pragma unroll
        for (int ocb = 0; ocb < 4; ++ocb) {
            int oc = ocb * 16 + l15;
            float scale = sc[oc], shift = sh[oc];
            float4 v;
            v.x = fmaxf(acc[ps][ocb][0] * scale + shift, 0.f);
            v.y = fmaxf(acc[ps][ocb][1] * scale + shift, 0.f);
            v.z = fmaxf(acc[ps][ocb][2] * scale + shift, 0.f);
            v.w = fmaxf(acc[ps][ocb][3] * scale + shift, 0.f);
            float* op = out + ((size_t)((bb * 16 + t) * 64 + oc)) * PX
                      + px0 + ps * 16 + l4 * 4;
            *reinterpret_cast<float4*>(op) = v;
        }
}

extern "C" void kernel_launch(void* const* d_in, const int* in_sizes, int n_in,
                              void* d_out, int out_size, void* d_ws, size_t ws_size,
                              hipStream_t stream) {
    const float* x     = (const float*)d_in[0];
    const float* Wf    = (const float*)d_in[1];
    const float* gnf_w = (const float*)d_in[2];
    const float* gnf_b = (const float*)d_in[3];
    const float* Wb    = (const float*)d_in[4];
    const float* gnb_w = (const float*)d_in[5];
    const float* gnb_b = (const float*)d_in[6];
    const float* Wfu   = (const float*)d_in[7];
    const float* bn_w  = (const float*)d_in[8];
    const float* bn_b  = (const float*)d_in[9];
    float* out = (float*)d_out;

    float* ws = (float*)d_ws;
    unsigned short* comb_t = (unsigned short*)ws;               // 16,777,216 f
    unsigned short* gatesb = (unsigned short*)(ws + 16777216);  //  4,194,304 f
    unsigned short* cbuf   = (unsigned short*)(ws + 20971520);  //  1,048,576 f
    float* gnstats = ws + 23068672;                             //      1,024 f
    float* bnparts = ws + 23069696;                             //      1,024 f
    unsigned short* W3    = (unsigned short*)(ws + 23070720);   //    294,912 f
    unsigned short* wfrag = (unsigned short*)(ws + 23365632);   //      4,096 f
    unsigned short* xb    = (unsigned short*)(ws + 23369728);   //  8,388,608 f

    // zero c (bf16 zeros == 0x0000), gn stats + bn partials
    hipMemsetAsync(cbuf, 0, (size_t)1048576 * 4, stream);
    hipMemsetAsync(gnstats, 0, (size_t)2048 * 4, stream);

    wconv3_kernel<<<2304, 256, 0, stream>>>(Wf, Wb, W3);
    wfu_pack_kernel<<<32, 256, 0, stream>>>(Wfu, wfrag);
    xconv_kernel<<<4096, 256, 0, stream>>>(x, xb);

    for (int s = 0; s < 16; ++s) {
        conv_mfma_kernel<<<512, 256, 0, stream>>>(
            xb, comb_t, W3, gatesb, gnstats, s);
        point_kernel2<<<1024, 256, 0, stream>>>(
            gatesb, gnstats, gnf_w, gnf_b, gnb_w, gnb_b, cbuf, comb_t, s);
    }
    fuse_stats2_kernel<<<1024, 256, 0, stream>>>(comb_t, wfrag, bnparts);
    bn_apply2_kernel<<<1024, 256, 0, stream>>>(comb_t, wfrag, bnparts, bn_w, bn_b, out);
}

// Round 14
// 876.590 us; speedup vs baseline: 1.4051x; 1.4051x over previous
//
#include <hip/hip_runtime.h>
#include <math.h>

#define PX 4096         // 64*64 spatial
#define EPS 1e-5f

typedef __attribute__((ext_vector_type(8))) __bf16 bf16x8;
typedef __attribute__((ext_vector_type(4))) float f32x4;

static __device__ __forceinline__ unsigned short f2b(float f) {
    unsigned int u = __float_as_uint(f);
    u += 0x7FFFu + ((u >> 16) & 1u);     // RTNE
    return (unsigned short)(u >> 16);
}
static __device__ __forceinline__ float b2f(unsigned short u) {
    return __uint_as_float((unsigned int)u << 16);
}
static __device__ __forceinline__ float rcpf(float x) {
    return __builtin_amdgcn_rcpf(x);
}

// ---------------------------------------------------------------------------
// ws layout (float units):
//   comb_t  bf16 [64 n][4096 px][128 ic]          16,777,216 f  @ 0
//   gatesb  bf16 [8 dirb][256 oc][4096 px]         4,194,304 f  @ 16,777,216
//   cbuf    bf16 [8 dirb][64 ch][4096]             1,048,576 f  @ 20,971,520
//   gnstat  f32  [16 s][2 dir][4 b][4 g][2]            1,024 f  @ 23,068,672
//   bnparts f32  [8 part][64 oc][2]                    1,024 f  @ 23,069,696
//   W3      bf16 [dir][ocblk][icblk][tap][mi][64 l][8 j] 294,912 f @ 23,070,720
//   wfrag   bf16 [4 ocb][4 icblk][64 l][8 j]           4,096 f  @ 23,365,632
//   xb      bf16 [64 bt][4096 px][64 ic]            8,388,608 f @ 23,369,728
//
// R14 conv = R13 structure (reg-rotated global weight fragments, single
// 21.8KB LDS input buffer) with launch_bounds(256,3): VGPR cap 170 fixes
// R13's catastrophic spill (R13 @(256,4): cap 128 -> acc spilled to scratch,
// WRITE_SIZE 16->85MB, 68us/step). 12 waves/CU vs R12's 8.
// ---------------------------------------------------------------------------

// Pack conv weights bf16 directly in per-lane MFMA A-fragment order.
__global__ __launch_bounds__(256) void wconv3_kernel(
    const float* __restrict__ Wf, const float* __restrict__ Wb,
    unsigned short* __restrict__ W3)
{
    int idx = blockIdx.x * 256 + threadIdx.x;
    if (idx >= 589824) return;
    int j = idx & 7;
    int l = (idx >> 3) & 63;
    int mi = (idx >> 9) & 3;
    int g = idx >> 11;            // ((dir*4+ocblk)*4+icblk)*9 + tap
    int tap = g % 9;
    int gg = g / 9;
    int icblk = gg & 3;
    int ocblk = (gg >> 2) & 3;
    int dir = gg >> 4;
    int oc = ocblk * 64 + mi * 16 + (l & 15);
    int ic = icblk * 32 + (l >> 4) * 8 + j;
    const float* __restrict__ W = dir ? Wb : Wf;
    W3[idx] = f2b(W[((size_t)oc * 128 + ic) * 9 + tap]);
}

// Pack Wfu into MFMA B-fragment order: [ocb][icblk][lane][j]
__global__ __launch_bounds__(256) void wfu_pack_kernel(
    const float* __restrict__ Wfu, unsigned short* __restrict__ wfrag)
{
    int idx = blockIdx.x * 256 + threadIdx.x;
    if (idx >= 8192) return;
    int j = idx & 7;
    int l = (idx >> 3) & 63;
    int icblk = (idx >> 9) & 3;
    int ocb = idx >> 11;
    int oc = ocb * 16 + (l & 15);
    int ic = icblk * 32 + (l >> 4) * 8 + j;
    wfrag[idx] = f2b(Wfu[oc * 128 + ic]);
}

// Transpose x to px-major bf16: xb[bt][px][64 ic].
__global__ __launch_bounds__(256) void xconv_kernel(
    const float* __restrict__ x, unsigned short* __restrict__ xb)
{
    int bt = blockIdx.x >> 6;
    int px0 = (blockIdx.x & 63) * 64;
    __shared__ unsigned short sh[64 * 72];
    int tid = threadIdx.x;
    {
        int px_l = tid & 63;
        int ic4 = tid >> 6;
        const float* __restrict__ src = x + (size_t)bt * 64 * PX + px0 + px_l;
#pragma unroll
        for (int k = 0; k < 16; ++k) {
            int ic = ic4 * 16 + k;
            sh[px_l * 72 + ic] = f2b(src[(size_t)ic * PX]);
        }
    }
    __syncthreads();
    {
        int px_w = tid >> 2;
        int ch = tid & 3;
        uint4 v0 = *reinterpret_cast<const uint4*>(&sh[px_w * 72 + ch * 16]);
        uint4 v1 = *reinterpret_cast<const uint4*>(&sh[px_w * 72 + ch * 16 + 8]);
        unsigned short* dst = xb + ((size_t)bt * PX + px0 + px_w) * 64 + ch * 16;
        *reinterpret_cast<uint4*>(dst) = v0;
        *reinterpret_cast<uint4*>(dst + 8) = v1;
    }
}

// K1: implicit-GEMM conv via MFMA.
// Weights: global->register fragments, 2-deep rotating prefetch (per-lane
// packed, read once per block). Input: single-buffer LDS halo tile.
// grid 512 (1-D): dirb = blockIdx&7 (XCD-local); rest: ocblk(4) x pxt(16).
__global__ __launch_bounds__(256, 3) void conv_mfma_kernel(
    const unsigned short* __restrict__ xb, const unsigned short* __restrict__ comb_t,
    const unsigned short* __restrict__ W3,
    unsigned short* __restrict__ gatesb, float* __restrict__ gnstats, int s)
{
    const int dirb = blockIdx.x & 7;
    const int rest = blockIdx.x >> 3;
    const int dir = dirb >> 2, b = dirb & 3;
    const int ocblk = rest >> 4;
    const int pxt = rest & 15;
    const int py0 = (pxt >> 1) * 8;
    const int pxc0 = (pxt & 1) * 32;
    const int t = dir ? (15 - s) : s;
    const int prev_t = dir ? (t + 1) : (t - 1);

    __shared__ __align__(16) unsigned short in_s[340 * 32];    // 21,760 B
    __shared__ float red[8];

    const int tid = threadIdx.x;
    const int w = tid >> 6;
    const int l = tid & 63;
    const int l15 = l & 15;
    const int l4 = l >> 4;

    const unsigned short* __restrict__ xpx = xb + (size_t)(b * 16 + t) * PX * 64;
    const unsigned short* __restrict__ hpx = comb_t
        + (size_t)(prev_t * 4 + b) * PX * 128 + dir * 64;
    const unsigned short* __restrict__ wbase = W3
        + (size_t)(dir * 4 + ocblk) * 36 * 2048 + l * 8;

    // staging address precompute (per-lane, reused each phase)
    int sg_px[6];      // global pixel index, -1 if out of tile
#pragma unroll
    for (int it = 0; it < 6; ++it) {
        int idx = tid + it * 256;
        int pl = idx >> 2;
        int row = (pl * 241) >> 13;          // pl / 34
        int col = pl - row * 34;
        int gy = py0 - 1 + row;
        int gx = pxc0 - 1 + col;
        bool valid = (idx < 1360) && ((unsigned)gy < 64u) && ((unsigned)gx < 64u);
        sg_px[it] = valid ? (gy * 64 + gx) : -1;
    }

    f32x4 acc[4][4];
#pragma unroll
    for (int i = 0; i < 4; ++i)
#pragma unroll
        for (int j = 0; j < 4; ++j)
            acc[i][j] = (f32x4){0.f, 0.f, 0.f, 0.f};

    // direct staging: load uint4 -> ds_write (latency hidden by 12 waves/CU)
    auto stage = [&](int icblk) {
        const bool useh = icblk >= 2;
        const unsigned short* __restrict__ srcpx = useh
            ? (hpx + (icblk - 2) * 32) : (xpx + icblk * 32);
        const int rec = useh ? 128 : 64;
        const bool zero = useh && (s == 0);
        const int c = tid & 3;
#pragma unroll
        for (int it = 0; it < 6; ++it) {
            int idx = tid + it * 256;
            if (idx < 1360) {
                int pl = idx >> 2;
                uint4 v = make_uint4(0u, 0u, 0u, 0u);
                if (sg_px[it] >= 0 && !zero)
                    v = *reinterpret_cast<const uint4*>(
                        srcpx + (size_t)sg_px[it] * rec + c * 8);
                int woff = pl * 32 + ((c ^ ((pl >> 1) & 3)) * 8);
                *reinterpret_cast<uint4*>(&in_s[woff]) = v;
            }
        }
    };

    bf16x8 av[2][4];
    auto loadW = [&](int slot, int g) {
#pragma unroll
        for (int mi = 0; mi < 4; ++mi)
            av[slot][mi] = *reinterpret_cast<const bf16x8*>(
                wbase + (size_t)(g * 4 + mi) * 512);
    };

    loadW(0, 0);

    for (int icblk = 0; icblk < 4; ++icblk) {
        __syncthreads();                 // prior compute done reading in_s
        stage(icblk);
        __syncthreads();                 // in_s ready

#pragma unroll
        for (int tap = 0; tap < 9; ++tap) {
            const int g = icblk * 9 + tap;
            if (g < 35) loadW((g + 1) & 1, g + 1);     // prefetch next frag
            const int dy = tap / 3, dx = tap % 3;
            bf16x8 bv[4];
#pragma unroll
            for (int ni = 0; ni < 4; ++ni) {
                int nr = ni >> 1, nc = ni & 1;
                int pl = (2 * w + nr + dy) * 34 + nc * 16 + l15 + dx;
                int boff = pl * 32 + ((l4 ^ ((pl >> 1) & 3)) * 8);
                bv[ni] = *reinterpret_cast<const bf16x8*>(&in_s[boff]);
            }
#pragma unroll
            for (int mi = 0; mi < 4; ++mi)
#pragma unroll
                for (int ni = 0; ni < 4; ++ni)
                    acc[mi][ni] = __builtin_amdgcn_mfma_f32_16x16x32_bf16(
                        av[g & 1][mi], bv[ni], acc[mi][ni], 0, 0, 0);
        }
    }

    // epilogue: write gates (bf16) + GN partial stats (fp32 from acc)
    float s1 = 0.f, s2 = 0.f;
    unsigned short* __restrict__ gbase = gatesb
        + ((size_t)dirb * 256 + (size_t)ocblk * 64) * PX;
#pragma unroll
    for (int mi = 0; mi < 4; ++mi)
#pragma unroll
        for (int ni = 0; ni < 4; ++ni) {
            int nr = ni >> 1, nc = ni & 1;
            int px = (py0 + 2 * w + nr) * 64 + pxc0 + nc * 16 + l15;
#pragma unroll
            for (int j = 0; j < 4; ++j) {
                float v = acc[mi][ni][j];
                int oc = mi * 16 + l4 * 4 + j;
                gbase[(size_t)oc * PX + px] = f2b(v);
                s1 += v;
                s2 += v * v;
            }
        }
    for (int off = 32; off; off >>= 1) {
        s1 += __shfl_down(s1, off);
        s2 += __shfl_down(s2, off);
    }
    if (l == 0) { red[w * 2] = s1; red[w * 2 + 1] = s2; }
    __syncthreads();
    if (tid == 0) {
        float a = red[0] + red[2] + red[4] + red[6];
        float q = red[1] + red[3] + red[5] + red[7];
        float* slot = gnstats + (((size_t)(s * 2 + dir) * 4 + b) * 4 + ocblk) * 2;
        atomicAdd(slot, a);
        atomicAdd(slot + 1, q);
    }
}

// K2: GN + activations + LSTM update; c stored bf16; h -> comb_t (bf16).
// grid 1024 (1-D): dirb = blockIdx&7 (XCD-local, same mapping as conv).
__global__ __launch_bounds__(256) void point_kernel2(
    const unsigned short* __restrict__ gatesb, const float* __restrict__ gnstats,
    const float* __restrict__ gnf_w, const float* __restrict__ gnf_b,
    const float* __restrict__ gnb_w, const float* __restrict__ gnb_b,
    unsigned short* __restrict__ cbuf, unsigned short* __restrict__ comb_t, int s)
{
    int dirb = blockIdx.x & 7;
    int idx = (blockIdx.x >> 3) * 256 + threadIdx.x;   // 0..32767 within dirb
    int pxl = idx & 7;
    int o8 = (idx >> 3) & 7;
    int pxh = idx >> 6;                                // 0..511
    int px = pxh * 8 + pxl;
    int dir = dirb >> 2, b = dirb & 3;

    __shared__ float gwl[256], gbl[256], mrs[8];
    int tid = threadIdx.x;
    {
        const float* __restrict__ gw = dir ? gnb_w : gnf_w;
        const float* __restrict__ gb = dir ? gnb_b : gnf_b;
        gwl[tid] = gw[tid];
        gbl[tid] = gb[tid];
    }
    if (tid < 4) {
        const float* slot = gnstats + ((size_t)(s * 2 + dir) * 4 + b) * 8 + tid * 2;
        const float invN = 1.0f / 262144.0f;
        float mean = slot[0] * invN;
        float var = slot[1] * invN - mean * mean;
        mrs[tid * 2] = mean;
        mrs[tid * 2 + 1] = rsqrtf(var + EPS);
    }
    __syncthreads();

    const unsigned short* __restrict__ gbase = gatesb + (size_t)dirb * 256 * PX + px;
    size_t cbase = ((size_t)dirb * 64 + o8 * 8) * PX + px;
    float m0 = mrs[0], r0 = mrs[1], m1 = mrs[2], r1 = mrs[3];
    float m2 = mrs[4], r2 = mrs[5], m3 = mrs[6], r3 = mrs[7];

    unsigned int packed[4];
#pragma unroll
    for (int cc = 0; cc < 8; ++cc) {
        int ch = o8 * 8 + cc;
        float g0 = b2f(gbase[(size_t)(ch) * PX]);
        float g1 = b2f(gbase[(size_t)(64 + ch) * PX]);
        float g2 = b2f(gbase[(size_t)(128 + ch) * PX]);
        float g3 = b2f(gbase[(size_t)(192 + ch) * PX]);
        float v0 = (g0 - m0) * r0 * gwl[ch] + gbl[ch];
        float v1 = (g1 - m1) * r1 * gwl[64 + ch] + gbl[64 + ch];
        float v2 = (g2 - m2) * r2 * gwl[128 + ch] + gbl[128 + ch];
        float v3 = (g3 - m3) * r3 * gwl[192 + ch] + gbl[192 + ch];
        float ig = rcpf(1.f + __expf(-v0));
        float fg = rcpf(1.f + __expf(-v1));
        float og = rcpf(1.f + __expf(-v2));
        float gg = 1.f - 2.f * rcpf(1.f + __expf(2.f * v3));
        float cold = b2f(cbuf[cbase + (size_t)cc * PX]);
        float cnew = fg * cold + ig * gg;
        float th = 1.f - 2.f * rcpf(1.f + __expf(2.f * cnew));
        float hnew = og * th;
        cbuf[cbase + (size_t)cc * PX] = f2b(cnew);
        unsigned int hb = (unsigned int)f2b(hnew);
        if (cc & 1) packed[cc >> 1] |= hb << 16;
        else        packed[cc >> 1] = hb;
    }
    int t = dir ? (15 - s) : s;
    size_t co = ((size_t)(t * 4 + b) * PX + px) * 128 + dir * 64 + o8 * 8;
    *reinterpret_cast<uint4*>(comb_t + co) =
        make_uint4(packed[0], packed[1], packed[2], packed[3]);
}

// K3: 1x1 fuse conv via MFMA; BN partial stats only.
__global__ __launch_bounds__(256) void fuse_stats2_kernel(
    const unsigned short* __restrict__ comb_t,
    const unsigned short* __restrict__ wfrag, float* __restrict__ bnparts)
{
    int n = blockIdx.x >> 4, pxb = blockIdx.x & 15;
    int tid = threadIdx.x;
    int w = tid >> 6, l = tid & 63;
    int l15 = l & 15, l4 = l >> 4;

    bf16x8 B[4][4];
#pragma unroll
    for (int ocb = 0; ocb < 4; ++ocb)
#pragma unroll
        for (int icblk = 0; icblk < 4; ++icblk)
            B[ocb][icblk] = *reinterpret_cast<const bf16x8*>(
                wfrag + (((ocb * 4 + icblk) * 64 + l) * 8));

    f32x4 acc[4][4];
#pragma unroll
    for (int i = 0; i < 4; ++i)
#pragma unroll
        for (int j = 0; j < 4; ++j)
            acc[i][j] = (f32x4){0.f, 0.f, 0.f, 0.f};

    int px0 = pxb * 256 + w * 64;
    const unsigned short* __restrict__ cb = comb_t + (size_t)n * PX * 128;
#pragma unroll
    for (int ps = 0; ps < 4; ++ps) {
        const unsigned short* ab = cb + (size_t)(px0 + ps * 16 + l15) * 128 + l4 * 8;
        bf16x8 A[4];
#pragma unroll
        for (int icblk = 0; icblk < 4; ++icblk)
            A[icblk] = *reinterpret_cast<const bf16x8*>(ab + icblk * 32);
#pragma unroll
        for (int icblk = 0; icblk < 4; ++icblk)
#pragma unroll
            for (int ocb = 0; ocb < 4; ++ocb)
                acc[ps][ocb] = __builtin_amdgcn_mfma_f32_16x16x32_bf16(
                    A[icblk], B[ocb][icblk], acc[ps][ocb], 0, 0, 0);
    }

    float s1[4] = {0, 0, 0, 0}, s2[4] = {0, 0, 0, 0};
#pragma unroll
    for (int ps = 0; ps < 4; ++ps)
#pragma unroll
        for (int ocb = 0; ocb < 4; ++ocb)
#pragma unroll
            for (int j = 0; j < 4; ++j) {
                float v = acc[ps][ocb][j];
                s1[ocb] += v;
                s2[ocb] += v * v;
            }
#pragma unroll
    for (int ocb = 0; ocb < 4; ++ocb) {
        s1[ocb] += __shfl_down(s1[ocb], 32);
        s1[ocb] += __shfl_down(s1[ocb], 16);
        s2[ocb] += __shfl_down(s2[ocb], 32);
        s2[ocb] += __shfl_down(s2[ocb], 16);
    }
    __shared__ float sred[4][4][16][2];
    if (l < 16)
#pragma unroll
        for (int ocb = 0; ocb < 4; ++ocb) {
            sred[w][ocb][l][0] = s1[ocb];
            sred[w][ocb][l][1] = s2[ocb];
        }
    __syncthreads();
    if (tid < 128) {
        int oc = tid >> 1, isq = tid & 1;
        float v = sred[0][oc >> 4][oc & 15][isq] + sred[1][oc >> 4][oc & 15][isq]
                + sred[2][oc >> 4][oc & 15][isq] + sred[3][oc >> 4][oc & 15][isq];
        atomicAdd(bnparts + (blockIdx.x & 7) * 128 + tid, v);
    }
}

// K4: recompute fuse MFMA, BN + ReLU, transposed store to out.
__global__ __launch_bounds__(256) void bn_apply2_kernel(
    const unsigned short* __restrict__ comb_t,
    const unsigned short* __restrict__ wfrag, const float* __restrict__ bnparts,
    const float* __restrict__ bn_w, const float* __restrict__ bn_b,
    float* __restrict__ out)
{
    int n = blockIdx.x >> 4, pxb = blockIdx.x & 15;
    int tid = threadIdx.x;
    int w = tid >> 6, l = tid & 63;
    int l15 = l & 15, l4 = l >> 4;

    __shared__ float sc[64], sh[64];
    if (tid < 64) {
        const float invN = 1.0f / 262144.0f;
        float S = 0.f, Q = 0.f;
#pragma unroll
        for (int p = 0; p < 8; ++p) {
            S += bnparts[p * 128 + tid * 2];
            Q += bnparts[p * 128 + tid * 2 + 1];
        }
        float mean = S * invN;
        float var = Q * invN - mean * mean;
        float scale = rsqrtf(var + EPS) * bn_w[tid];
        sc[tid] = scale;
        sh[tid] = bn_b[tid] - mean * scale;
    }

    bf16x8 B[4][4];
#pragma unroll
    for (int ocb = 0; ocb < 4; ++ocb)
#pragma unroll
        for (int icblk = 0; icblk < 4; ++icblk)
            B[ocb][icblk] = *reinterpret_cast<const bf16x8*>(
                wfrag + (((ocb * 4 + icblk) * 64 + l) * 8));
    __syncthreads();

    f32x4 acc[4][4];
#pragma unroll
    for (int i = 0; i < 4; ++i)
#pragma unroll
        for (int j = 0; j < 4; ++j)
            acc[i][j] = (f32x4){0.f, 0.f, 0.f, 0.f};

    int px0 = pxb * 256 + w * 64;
    const unsigned short* __restrict__ cb = comb_t + (size_t)n * PX * 128;
#pragma unroll
    for (int ps = 0; ps < 4; ++ps) {
        const unsigned short* ab = cb + (size_t)(px0 + ps * 16 + l15) * 128 + l4 * 8;
        bf16x8 A[4];
#pragma unroll
        for (int icblk = 0; icblk < 4; ++icblk)
            A[icblk] = *reinterpret_cast<const bf16x8*>(ab + icblk * 32);
#pragma unroll
        for (int icblk = 0; icblk < 4; ++icblk)
#pragma unroll
            for (int ocb = 0; ocb < 4; ++ocb)
                acc[ps][ocb] = __builtin_amdgcn_mfma_f32_16x16x32_bf16(
                    A[icblk], B[ocb][icblk], acc[ps][ocb], 0, 0, 0);
    }

    int t = n >> 2, bb = n & 3;
#pragma unroll
    for (int ps = 0; ps < 4; ++ps)
#pragma unroll
        for (int ocb = 0; ocb < 4; ++ocb) {
            int oc = ocb * 16 + l15;
            float scale = sc[oc], shift = sh[oc];
            float4 v;
            v.x = fmaxf(acc[ps][ocb][0] * scale + shift, 0.f);
            v.y = fmaxf(acc[ps][ocb][1] * scale + shift, 0.f);
            v.z = fmaxf(acc[ps][ocb][2] * scale + shift, 0.f);
            v.w = fmaxf(acc[ps][ocb][3] * scale + shift, 0.f);
            float* op = out + ((size_t)((bb * 16 + t) * 64 + oc)) * PX
                      + px0 + ps * 16 + l4 * 4;
            *reinterpret_cast<float4*>(op) = v;
        }
}

extern "C" void kernel_launch(void* const* d_in, const int* in_sizes, int n_in,
                              void* d_out, int out_size, void* d_ws, size_t ws_size,
                              hipStream_t stream) {
    const float* x     = (const float*)d_in[0];
    const float* Wf    = (const float*)d_in[1];
    const float* gnf_w = (const float*)d_in[2];
    const float* gnf_b = (const float*)d_in[3];
    const float* Wb    = (const float*)d_in[4];
    const float* gnb_w = (const float*)d_in[5];
    const float* gnb_b = (const float*)d_in[6];
    const float* Wfu   = (const float*)d_in[7];
    const float* bn_w  = (const float*)d_in[8];
    const float* bn_b  = (const float*)d_in[9];
    float* out = (float*)d_out;

    float* ws = (float*)d_ws;
    unsigned short* comb_t = (unsigned short*)ws;               // 16,777,216 f
    unsigned short* gatesb = (unsigned short*)(ws + 16777216);  //  4,194,304 f
    unsigned short* cbuf   = (unsigned short*)(ws + 20971520);  //  1,048,576 f
    float* gnstats = ws + 23068672;                             //      1,024 f
    float* bnparts = ws + 23069696;                             //      1,024 f
    unsigned short* W3    = (unsigned short*)(ws + 23070720);   //    294,912 f
    unsigned short* wfrag = (unsigned short*)(ws + 23365632);   //      4,096 f
    unsigned short* xb    = (unsigned short*)(ws + 23369728);   //  8,388,608 f

    // zero c (bf16 zeros == 0x0000), gn stats + bn partials
    hipMemsetAsync(cbuf, 0, (size_t)1048576 * 4, stream);
    hipMemsetAsync(gnstats, 0, (size_t)2048 * 4, stream);

    wconv3_kernel<<<2304, 256, 0, stream>>>(Wf, Wb, W3);
    wfu_pack_kernel<<<32, 256, 0, stream>>>(Wfu, wfrag);
    xconv_kernel<<<4096, 256, 0, stream>>>(x, xb);

    for (int s = 0; s < 16; ++s) {
        conv_mfma_kernel<<<512, 256, 0, stream>>>(
            xb, comb_t, W3, gatesb, gnstats, s);
        point_kernel2<<<1024, 256, 0, stream>>>(
            gatesb, gnstats, gnf_w, gnf_b, gnb_w, gnb_b, cbuf, comb_t, s);
    }
    fuse_stats2_kernel<<<1024, 256, 0, stream>>>(comb_t, wfrag, bnparts);
    bn_apply2_kernel<<<1024, 256, 0, stream>>>(comb_t, wfrag, bnparts, bn_w, bn_b, out);
}

// Round 15
// 622.108 us; speedup vs baseline: 1.9799x; 1.4091x over previous
//
#include <hip/hip_runtime.h>
#include <math.h>

#define PX 4096         // 64*64 spatial
#define EPS 1e-5f

typedef __attribute__((ext_vector_type(8))) __bf16 bf16x8;
typedef __attribute__((ext_vector_type(4))) float f32x4;

static __device__ __forceinline__ unsigned short f2b(float f) {
    unsigned int u = __float_as_uint(f);
    u += 0x7FFFu + ((u >> 16) & 1u);     // RTNE
    return (unsigned short)(u >> 16);
}
static __device__ __forceinline__ float b2f(unsigned short u) {
    return __uint_as_float((unsigned int)u << 16);
}
static __device__ __forceinline__ float rcpf(float x) {
    return __builtin_amdgcn_rcpf(x);
}

// ---------------------------------------------------------------------------
// ws layout (float units):
//   comb_t  bf16 [64 n][4096 px][128 ic]          16,777,216 f  @ 0
//   gatesb  bf16 [8 dirb][256 oc][4096 px]         4,194,304 f  @ 16,777,216
//   cbuf    bf16 [8 dirb][64 ch][4096]             1,048,576 f  @ 20,971,520
//   gnstat  f32  [16 s][2 dir][4 b][4 g][2]            1,024 f  @ 23,068,672
//   bnparts f32  [8 part][64 oc][2]                    1,024 f  @ 23,069,696
//   W2s     bf16 [dir][ocblk][icblk][tap][64][4][8] 294,912 f  @ 23,070,720
//   wfrag   bf16 [4 ocb][4 icblk][64 l][8 j]           4,096 f  @ 23,365,632
//   xb      bf16 [64 bt][4096 px][64 ic]            8,388,608 f @ 23,369,728
//
// R15 = R12 verbatim (measured best, 616 us): conv with LDS pre-swizzled
// weights + 2-barrier phases, XCD-local 1-D grid (dirb=blockIdx&7), bf16 c.
// Structural alternatives measured and rejected: reg-weights (spills: R13/14),
// smaller tiles (2x weight traffic: R11), in-kernel GN fusion via spin
// all-reduce (barrier cost: R10), cooperative persistence (L2 flush per
// grid.sync: R8).
// ---------------------------------------------------------------------------

// Pack conv weights bf16, pre-swizzled to the conv kernel's LDS image.
__global__ __launch_bounds__(256) void wconv2_kernel(
    const float* __restrict__ Wf, const float* __restrict__ Wb,
    unsigned short* __restrict__ W2s)
{
    int idx = blockIdx.x * 256 + threadIdx.x;
    if (idx >= 589824) return;
    int within = idx & 2047;
    int grp = idx >> 11;
    int oc = within >> 5;
    int slot = (within >> 3) & 3;
    int j = within & 7;
    int tap = grp % 9;
    int rest = grp / 9;
    int icblk = rest & 3;
    int ocblk = (rest >> 2) & 3;
    int dir = rest >> 4;
    int c = slot ^ ((oc >> 1) & 3);
    int ic = icblk * 32 + c * 8 + j;
    int OC = ocblk * 64 + oc;
    const float* __restrict__ W = dir ? Wb : Wf;
    W2s[idx] = f2b(W[((size_t)OC * 128 + ic) * 9 + tap]);
}

// Pack Wfu into MFMA B-fragment order: [ocb][icblk][lane][j]
__global__ __launch_bounds__(256) void wfu_pack_kernel(
    const float* __restrict__ Wfu, unsigned short* __restrict__ wfrag)
{
    int idx = blockIdx.x * 256 + threadIdx.x;
    if (idx >= 8192) return;
    int j = idx & 7;
    int l = (idx >> 3) & 63;
    int icblk = (idx >> 9) & 3;
    int ocb = idx >> 11;
    int oc = ocb * 16 + (l & 15);
    int ic = icblk * 32 + (l >> 4) * 8 + j;
    wfrag[idx] = f2b(Wfu[oc * 128 + ic]);
}

// Transpose x to px-major bf16: xb[bt][px][64 ic].
__global__ __launch_bounds__(256) void xconv_kernel(
    const float* __restrict__ x, unsigned short* __restrict__ xb)
{
    int bt = blockIdx.x >> 6;
    int px0 = (blockIdx.x & 63) * 64;
    __shared__ unsigned short sh[64 * 72];
    int tid = threadIdx.x;
    {
        int px_l = tid & 63;
        int ic4 = tid >> 6;
        const float* __restrict__ src = x + (size_t)bt * 64 * PX + px0 + px_l;
#pragma unroll
        for (int k = 0; k < 16; ++k) {
            int ic = ic4 * 16 + k;
            sh[px_l * 72 + ic] = f2b(src[(size_t)ic * PX]);
        }
    }
    __syncthreads();
    {
        int px_w = tid >> 2;
        int ch = tid & 3;
        uint4 v0 = *reinterpret_cast<const uint4*>(&sh[px_w * 72 + ch * 16]);
        uint4 v1 = *reinterpret_cast<const uint4*>(&sh[px_w * 72 + ch * 16 + 8]);
        unsigned short* dst = xb + ((size_t)bt * PX + px0 + px_w) * 64 + ch * 16;
        *reinterpret_cast<uint4*>(dst) = v0;
        *reinterpret_cast<uint4*>(dst + 8) = v1;
    }
}

// K1: implicit-GEMM conv via MFMA (R5 structure). Staging = pure uint4 copies.
// grid 512 (1-D): dirb = blockIdx&7 (XCD-local); rest: ocblk(4) x pxt(16).
__global__ __launch_bounds__(256, 2) void conv_mfma_kernel(
    const unsigned short* __restrict__ xb, const unsigned short* __restrict__ comb_t,
    const unsigned short* __restrict__ W2s,
    unsigned short* __restrict__ gatesb, float* __restrict__ gnstats, int s)
{
    const int dirb = blockIdx.x & 7;
    const int rest = blockIdx.x >> 3;
    const int dir = dirb >> 2, b = dirb & 3;
    const int ocblk = rest >> 4;
    const int pxt = rest & 15;
    const int py0 = (pxt >> 1) * 8;
    const int pxc0 = (pxt & 1) * 32;
    const int t = dir ? (15 - s) : s;
    const int prev_t = dir ? (t + 1) : (t - 1);

    __shared__ __align__(16) unsigned short Wl[9 * 64 * 32];   // 36,864 B
    __shared__ __align__(16) unsigned short in_s[340 * 32];    // 21,760 B
    __shared__ float red[8];

    const int tid = threadIdx.x;
    const int w = tid >> 6;
    const int l = tid & 63;
    const int l15 = l & 15;
    const int l4 = l >> 4;

    const unsigned short* __restrict__ xpx = xb + (size_t)(b * 16 + t) * PX * 64;
    const unsigned short* __restrict__ hpx = comb_t
        + (size_t)(prev_t * 4 + b) * PX * 128 + dir * 64;

    f32x4 acc[4][4];
#pragma unroll
    for (int i = 0; i < 4; ++i)
#pragma unroll
        for (int j = 0; j < 4; ++j)
            acc[i][j] = (f32x4){0.f, 0.f, 0.f, 0.f};

    for (int icblk = 0; icblk < 4; ++icblk) {
        __syncthreads();
        // ---- stage weights: straight 36,864-B copy (pre-swizzled)
        {
            const unsigned short* __restrict__ wsrc = W2s
                + ((size_t)((dir * 4 + ocblk) * 4 + icblk) * 9) * 2048;
#pragma unroll
            for (int it = 0; it < 9; ++it) {
                int e = tid + it * 256;
                *reinterpret_cast<uint4*>(&Wl[e * 8]) =
                    *reinterpret_cast<const uint4*>(wsrc + e * 8);
            }
        }
        // ---- stage input halo tile: 340 px x 32 ic (uint4 per lane)
        {
            const bool useh = icblk >= 2;
            const unsigned short* __restrict__ srcpx = useh
                ? (hpx + (icblk - 2) * 32) : (xpx + icblk * 32);
            const int rec = useh ? 128 : 64;
            const bool zero = useh && (s == 0);
#pragma unroll
            for (int it = 0; it < 6; ++it) {
                int idx = tid + it * 256;
                if (idx < 1360) {
                    int c = idx & 3;
                    int pl = idx >> 2;
                    int row = (pl * 241) >> 13;      // pl / 34
                    int col = pl - row * 34;
                    int gy = py0 - 1 + row;
                    int gx = pxc0 - 1 + col;
                    bool valid = ((unsigned)gy < 64u) && ((unsigned)gx < 64u) && !zero;
                    uint4 v = make_uint4(0u, 0u, 0u, 0u);
                    if (valid)
                        v = *reinterpret_cast<const uint4*>(
                            srcpx + (size_t)(gy * 64 + gx) * rec + c * 8);
                    int woff = pl * 32 + ((c ^ ((pl >> 1) & 3)) * 8);
                    *reinterpret_cast<uint4*>(&in_s[woff]) = v;
                }
            }
        }
        __syncthreads();

        // ---- 9 taps x 16 MFMA
#pragma unroll
        for (int tap = 0; tap < 9; ++tap) {
            const int dy = tap / 3, dx = tap % 3;
            bf16x8 av[4], bv[4];
#pragma unroll
            for (int mi = 0; mi < 4; ++mi) {
                int oc = mi * 16 + l15;
                int aoff = tap * 2048 + oc * 32 + ((l4 ^ ((oc >> 1) & 3)) * 8);
                av[mi] = *reinterpret_cast<const bf16x8*>(&Wl[aoff]);
            }
#pragma unroll
            for (int ni = 0; ni < 4; ++ni) {
                int nr = ni >> 1, nc = ni & 1;
                int pl = (2 * w + nr + dy) * 34 + nc * 16 + l15 + dx;
                int boff = pl * 32 + ((l4 ^ ((pl >> 1) & 3)) * 8);
                bv[ni] = *reinterpret_cast<const bf16x8*>(&in_s[boff]);
            }
#pragma unroll
            for (int mi = 0; mi < 4; ++mi)
#pragma unroll
                for (int ni = 0; ni < 4; ++ni)
                    acc[mi][ni] = __builtin_amdgcn_mfma_f32_16x16x32_bf16(
                        av[mi], bv[ni], acc[mi][ni], 0, 0, 0);
        }
    }

    // epilogue: write gates (bf16) + GN partial stats (fp32 from acc)
    float s1 = 0.f, s2 = 0.f;
    unsigned short* __restrict__ gbase = gatesb
        + ((size_t)dirb * 256 + (size_t)ocblk * 64) * PX;
#pragma unroll
    for (int mi = 0; mi < 4; ++mi)
#pragma unroll
        for (int ni = 0; ni < 4; ++ni) {
            int nr = ni >> 1, nc = ni & 1;
            int px = (py0 + 2 * w + nr) * 64 + pxc0 + nc * 16 + l15;
#pragma unroll
            for (int j = 0; j < 4; ++j) {
                float v = acc[mi][ni][j];
                int oc = mi * 16 + l4 * 4 + j;
                gbase[(size_t)oc * PX + px] = f2b(v);
                s1 += v;
                s2 += v * v;
            }
        }
    for (int off = 32; off; off >>= 1) {
        s1 += __shfl_down(s1, off);
        s2 += __shfl_down(s2, off);
    }
    if (l == 0) { red[w * 2] = s1; red[w * 2 + 1] = s2; }
    __syncthreads();
    if (tid == 0) {
        float a = red[0] + red[2] + red[4] + red[6];
        float q = red[1] + red[3] + red[5] + red[7];
        float* slot = gnstats + (((size_t)(s * 2 + dir) * 4 + b) * 4 + ocblk) * 2;
        atomicAdd(slot, a);
        atomicAdd(slot + 1, q);
    }
}

// K2: GN + activations + LSTM update; c stored bf16; h -> comb_t (bf16).
// grid 1024 (1-D): dirb = blockIdx&7 (XCD-local, same mapping as conv).
__global__ __launch_bounds__(256) void point_kernel2(
    const unsigned short* __restrict__ gatesb, const float* __restrict__ gnstats,
    const float* __restrict__ gnf_w, const float* __restrict__ gnf_b,
    const float* __restrict__ gnb_w, const float* __restrict__ gnb_b,
    unsigned short* __restrict__ cbuf, unsigned short* __restrict__ comb_t, int s)
{
    int dirb = blockIdx.x & 7;
    int idx = (blockIdx.x >> 3) * 256 + threadIdx.x;   // 0..32767 within dirb
    int pxl = idx & 7;
    int o8 = (idx >> 3) & 7;
    int pxh = idx >> 6;                                // 0..511
    int px = pxh * 8 + pxl;
    int dir = dirb >> 2, b = dirb & 3;

    __shared__ float gwl[256], gbl[256], mrs[8];
    int tid = threadIdx.x;
    {
        const float* __restrict__ gw = dir ? gnb_w : gnf_w;
        const float* __restrict__ gb = dir ? gnb_b : gnf_b;
        gwl[tid] = gw[tid];
        gbl[tid] = gb[tid];
    }
    if (tid < 4) {
        const float* slot = gnstats + ((size_t)(s * 2 + dir) * 4 + b) * 8 + tid * 2;
        const float invN = 1.0f / 262144.0f;
        float mean = slot[0] * invN;
        float var = slot[1] * invN - mean * mean;
        mrs[tid * 2] = mean;
        mrs[tid * 2 + 1] = rsqrtf(var + EPS);
    }
    __syncthreads();

    const unsigned short* __restrict__ gbase = gatesb + (size_t)dirb * 256 * PX + px;
    size_t cbase = ((size_t)dirb * 64 + o8 * 8) * PX + px;
    float m0 = mrs[0], r0 = mrs[1], m1 = mrs[2], r1 = mrs[3];
    float m2 = mrs[4], r2 = mrs[5], m3 = mrs[6], r3 = mrs[7];

    unsigned int packed[4];
#pragma unroll
    for (int cc = 0; cc < 8; ++cc) {
        int ch = o8 * 8 + cc;
        float g0 = b2f(gbase[(size_t)(ch) * PX]);
        float g1 = b2f(gbase[(size_t)(64 + ch) * PX]);
        float g2 = b2f(gbase[(size_t)(128 + ch) * PX]);
        float g3 = b2f(gbase[(size_t)(192 + ch) * PX]);
        float v0 = (g0 - m0) * r0 * gwl[ch] + gbl[ch];
        float v1 = (g1 - m1) * r1 * gwl[64 + ch] + gbl[64 + ch];
        float v2 = (g2 - m2) * r2 * gwl[128 + ch] + gbl[128 + ch];
        float v3 = (g3 - m3) * r3 * gwl[192 + ch] + gbl[192 + ch];
        float ig = rcpf(1.f + __expf(-v0));
        float fg = rcpf(1.f + __expf(-v1));
        float og = rcpf(1.f + __expf(-v2));
        float gg = 1.f - 2.f * rcpf(1.f + __expf(2.f * v3));
        float cold = b2f(cbuf[cbase + (size_t)cc * PX]);
        float cnew = fg * cold + ig * gg;
        float th = 1.f - 2.f * rcpf(1.f + __expf(2.f * cnew));
        float hnew = og * th;
        cbuf[cbase + (size_t)cc * PX] = f2b(cnew);
        unsigned int hb = (unsigned int)f2b(hnew);
        if (cc & 1) packed[cc >> 1] |= hb << 16;
        else        packed[cc >> 1] = hb;
    }
    int t = dir ? (15 - s) : s;
    size_t co = ((size_t)(t * 4 + b) * PX + px) * 128 + dir * 64 + o8 * 8;
    *reinterpret_cast<uint4*>(comb_t + co) =
        make_uint4(packed[0], packed[1], packed[2], packed[3]);
}

// K3: 1x1 fuse conv via MFMA; BN partial stats only.
__global__ __launch_bounds__(256) void fuse_stats2_kernel(
    const unsigned short* __restrict__ comb_t,
    const unsigned short* __restrict__ wfrag, float* __restrict__ bnparts)
{
    int n = blockIdx.x >> 4, pxb = blockIdx.x & 15;
    int tid = threadIdx.x;
    int w = tid >> 6, l = tid & 63;
    int l15 = l & 15, l4 = l >> 4;

    bf16x8 B[4][4];
#pragma unroll
    for (int ocb = 0; ocb < 4; ++ocb)
#pragma unroll
        for (int icblk = 0; icblk < 4; ++icblk)
            B[ocb][icblk] = *reinterpret_cast<const bf16x8*>(
                wfrag + (((ocb * 4 + icblk) * 64 + l) * 8));

    f32x4 acc[4][4];
#pragma unroll
    for (int i = 0; i < 4; ++i)
#pragma unroll
        for (int j = 0; j < 4; ++j)
            acc[i][j] = (f32x4){0.f, 0.f, 0.f, 0.f};

    int px0 = pxb * 256 + w * 64;
    const unsigned short* __restrict__ cb = comb_t + (size_t)n * PX * 128;
#pragma unroll
    for (int ps = 0; ps < 4; ++ps) {
        const unsigned short* ab = cb + (size_t)(px0 + ps * 16 + l15) * 128 + l4 * 8;
        bf16x8 A[4];
#pragma unroll
        for (int icblk = 0; icblk < 4; ++icblk)
            A[icblk] = *reinterpret_cast<const bf16x8*>(ab + icblk * 32);
#pragma unroll
        for (int icblk = 0; icblk < 4; ++icblk)
#pragma unroll
            for (int ocb = 0; ocb < 4; ++ocb)
                acc[ps][ocb] = __builtin_amdgcn_mfma_f32_16x16x32_bf16(
                    A[icblk], B[ocb][icblk], acc[ps][ocb], 0, 0, 0);
    }

    float s1[4] = {0, 0, 0, 0}, s2[4] = {0, 0, 0, 0};
#pragma unroll
    for (int ps = 0; ps < 4; ++ps)
#pragma unroll
        for (int ocb = 0; ocb < 4; ++ocb)
#pragma unroll
            for (int j = 0; j < 4; ++j) {
                float v = acc[ps][ocb][j];
                s1[ocb] += v;
                s2[ocb] += v * v;
            }
#pragma unroll
    for (int ocb = 0; ocb < 4; ++ocb) {
        s1[ocb] += __shfl_down(s1[ocb], 32);
        s1[ocb] += __shfl_down(s1[ocb], 16);
        s2[ocb] += __shfl_down(s2[ocb], 32);
        s2[ocb] += __shfl_down(s2[ocb], 16);
    }
    __shared__ float sred[4][4][16][2];
    if (l < 16)
#pragma unroll
        for (int ocb = 0; ocb < 4; ++ocb) {
            sred[w][ocb][l][0] = s1[ocb];
            sred[w][ocb][l][1] = s2[ocb];
        }
    __syncthreads();
    if (tid < 128) {
        int oc = tid >> 1, isq = tid & 1;
        float v = sred[0][oc >> 4][oc & 15][isq] + sred[1][oc >> 4][oc & 15][isq]
                + sred[2][oc >> 4][oc & 15][isq] + sred[3][oc >> 4][oc & 15][isq];
        atomicAdd(bnparts + (blockIdx.x & 7) * 128 + tid, v);
    }
}

// K4: recompute fuse MFMA, BN + ReLU, transposed store to out.
__global__ __launch_bounds__(256) void bn_apply2_kernel(
    const unsigned short* __restrict__ comb_t,
    const unsigned short* __restrict__ wfrag, const float* __restrict__ bnparts,
    const float* __restrict__ bn_w, const float* __restrict__ bn_b,
    float* __restrict__ out)
{
    int n = blockIdx.x >> 4, pxb = blockIdx.x & 15;
    int tid = threadIdx.x;
    int w = tid >> 6, l = tid & 63;
    int l15 = l & 15, l4 = l >> 4;

    __shared__ float sc[64], sh[64];
    if (tid < 64) {
        const float invN = 1.0f / 262144.0f;
        float S = 0.f, Q = 0.f;
#pragma unroll
        for (int p = 0; p < 8; ++p) {
            S += bnparts[p * 128 + tid * 2];
            Q += bnparts[p * 128 + tid * 2 + 1];
        }
        float mean = S * invN;
        float var = Q * invN - mean * mean;
        float scale = rsqrtf(var + EPS) * bn_w[tid];
        sc[tid] = scale;
        sh[tid] = bn_b[tid] - mean * scale;
    }

    bf16x8 B[4][4];
#pragma unroll
    for (int ocb = 0; ocb < 4; ++ocb)
#pragma unroll
        for (int icblk = 0; icblk < 4; ++icblk)
            B[ocb][icblk] = *reinterpret_cast<const bf16x8*>(
                wfrag + (((ocb * 4 + icblk) * 64 + l) * 8));
    __syncthreads();

    f32x4 acc[4][4];
#pragma unroll
    for (int i = 0; i < 4; ++i)
#pragma unroll
        for (int j = 0; j < 4; ++j)
            acc[i][j] = (f32x4){0.f, 0.f, 0.f, 0.f};

    int px0 = pxb * 256 + w * 64;
    const unsigned short* __restrict__ cb = comb_t + (size_t)n * PX * 128;
#pragma unroll
    for (int ps = 0; ps < 4; ++ps) {
        const unsigned short* ab = cb + (size_t)(px0 + ps * 16 + l15) * 128 + l4 * 8;
        bf16x8 A[4];
#pragma unroll
        for (int icblk = 0; icblk < 4; ++icblk)
            A[icblk] = *reinterpret_cast<const bf16x8*>(ab + icblk * 32);
#pragma unroll
        for (int icblk = 0; icblk < 4; ++icblk)
#pragma unroll
            for (int ocb = 0; ocb < 4; ++ocb)
                acc[ps][ocb] = __builtin_amdgcn_mfma_f32_16x16x32_bf16(
                    A[icblk], B[ocb][icblk], acc[ps][ocb], 0, 0, 0);
    }

    int t = n >> 2, bb = n & 3;
#pragma unroll
    for (int ps = 0; ps < 4; ++ps)
#pragma unroll
        for (int ocb = 0; ocb < 4; ++ocb) {
            int oc = ocb * 16 + l15;
            float scale = sc[oc], shift = sh[oc];
            float4 v;
            v.x = fmaxf(acc[ps][ocb][0] * scale + shift, 0.f);
            v.y = fmaxf(acc[ps][ocb][1] * scale + shift, 0.f);
            v.z = fmaxf(acc[ps][ocb][2] * scale + shift, 0.f);
            v.w = fmaxf(acc[ps][ocb][3] * scale + shift, 0.f);
            float* op = out + ((size_t)((bb * 16 + t) * 64 + oc)) * PX
                      + px0 + ps * 16 + l4 * 4;
            *reinterpret_cast<float4*>(op) = v;
        }
}

extern "C" void kernel_launch(void* const* d_in, const int* in_sizes, int n_in,
                              void* d_out, int out_size, void* d_ws, size_t ws_size,
                              hipStream_t stream) {
    const float* x     = (const float*)d_in[0];
    const float* Wf    = (const float*)d_in[1];
    const float* gnf_w = (const float*)d_in[2];
    const float* gnf_b = (const float*)d_in[3];
    const float* Wb    = (const float*)d_in[4];
    const float* gnb_w = (const float*)d_in[5];
    const float* gnb_b = (const float*)d_in[6];
    const float* Wfu   = (const float*)d_in[7];
    const float* bn_w  = (const float*)d_in[8];
    const float* bn_b  = (const float*)d_in[9];
    float* out = (float*)d_out;

    float* ws = (float*)d_ws;
    unsigned short* comb_t = (unsigned short*)ws;               // 16,777,216 f
    unsigned short* gatesb = (unsigned short*)(ws + 16777216);  //  4,194,304 f
    unsigned short* cbuf   = (unsigned short*)(ws + 20971520);  //  1,048,576 f
    float* gnstats = ws + 23068672;                             //      1,024 f
    float* bnparts = ws + 23069696;                             //      1,024 f
    unsigned short* W2s   = (unsigned short*)(ws + 23070720);   //    294,912 f
    unsigned short* wfrag = (unsigned short*)(ws + 23365632);   //      4,096 f
    unsigned short* xb    = (unsigned short*)(ws + 23369728);   //  8,388,608 f

    // zero c (bf16 zeros == 0x0000), gn stats + bn partials
    hipMemsetAsync(cbuf, 0, (size_t)1048576 * 4, stream);
    hipMemsetAsync(gnstats, 0, (size_t)2048 * 4, stream);

    wconv2_kernel<<<2304, 256, 0, stream>>>(Wf, Wb, W2s);
    wfu_pack_kernel<<<32, 256, 0, stream>>>(Wfu, wfrag);
    xconv_kernel<<<4096, 256, 0, stream>>>(x, xb);

    for (int s = 0; s < 16; ++s) {
        conv_mfma_kernel<<<512, 256, 0, stream>>>(
            xb, comb_t, W2s, gatesb, gnstats, s);
        point_kernel2<<<1024, 256, 0, stream>>>(
            gatesb, gnstats, gnf_w, gnf_b, gnb_w, gnb_b, cbuf, comb_t, s);
    }
    fuse_stats2_kernel<<<1024, 256, 0, stream>>>(comb_t, wfrag, bnparts);
    bn_apply2_kernel<<<1024, 256, 0, stream>>>(comb_t, wfrag, bnparts, bn_w, bn_b, out);
}

// Round 16
// 606.941 us; speedup vs baseline: 2.0293x; 1.0250x over previous
//
#include <hip/hip_runtime.h>
#include <math.h>

#define PX 4096         // 64*64 spatial
#define EPS 1e-5f

typedef __attribute__((ext_vector_type(8))) __bf16 bf16x8;
typedef __attribute__((ext_vector_type(4))) float f32x4;

static __device__ __forceinline__ unsigned short f2b(float f) {
    unsigned int u = __float_as_uint(f);
    u += 0x7FFFu + ((u >> 16) & 1u);     // RTNE
    return (unsigned short)(u >> 16);
}
static __device__ __forceinline__ float b2f(unsigned short u) {
    return __uint_as_float((unsigned int)u << 16);
}
static __device__ __forceinline__ float rcpf(float x) {
    return __builtin_amdgcn_rcpf(x);
}

// ---------------------------------------------------------------------------
// ws layout (float units):
//   comb_t  bf16 [64 n][4096 px][128 ic]          16,777,216 f  @ 0
//   gatesb  bf16 [8 dirb][256 oc][4096 px]         4,194,304 f  @ 16,777,216
//   cbuf    bf16 [8 dirb][64 ch][4096]             1,048,576 f  @ 20,971,520
//   gnstat  f32  [16 s][2 dir][4 b][4 g][2]            1,024 f  @ 22,020,096
//   bnparts f32  [8 part][64 oc][2]                    1,024 f  @ 22,021,120
//   W2s     bf16 [dir][ocblk][icblk][tap][64][4][8] 294,912 f  @ 22,022,144
//   wfrag   bf16 [4 ocb][4 icblk][64 l][8 j]           4,096 f  @ 22,317,056
//   xb      bf16 [64 bt][4096 px][64 ic]            8,388,608 f @ 22,321,152
//
// R16 = R12/R15 (measured optimum, 616-622us) + launch consolidation:
// one pack kernel (W2s + wfrag), one memset (cbuf..bnparts contiguous).
// Structural alternatives measured and rejected this session:
//   reg-weights (allocator spills: R6/R13/R14), smaller tiles (2x weight
//   traffic: R11), in-kernel GN fusion via spin all-reduce (inter-block
//   sync >> launch cost: R10), cooperative persistence (L2 flush per
//   grid.sync: R8), occupancy via LDS cut (spills: R13/R14).
// ---------------------------------------------------------------------------

// Pack conv weights (pre-swizzled LDS image) + Wfu B-fragments, one launch.
__global__ __launch_bounds__(256) void pack_kernel(
    const float* __restrict__ Wf, const float* __restrict__ Wb,
    const float* __restrict__ Wfu,
    unsigned short* __restrict__ W2s, unsigned short* __restrict__ wfrag)
{
    int idx = blockIdx.x * 256 + threadIdx.x;
    if (idx < 589824) {
        int within = idx & 2047;
        int grp = idx >> 11;
        int oc = within >> 5;
        int slot = (within >> 3) & 3;
        int j = within & 7;
        int tap = grp % 9;
        int rest = grp / 9;
        int icblk = rest & 3;
        int ocblk = (rest >> 2) & 3;
        int dir = rest >> 4;
        int c = slot ^ ((oc >> 1) & 3);
        int ic = icblk * 32 + c * 8 + j;
        int OC = ocblk * 64 + oc;
        const float* __restrict__ W = dir ? Wb : Wf;
        W2s[idx] = f2b(W[((size_t)OC * 128 + ic) * 9 + tap]);
    } else if (idx < 589824 + 8192) {
        int k = idx - 589824;
        int j = k & 7;
        int l = (k >> 3) & 63;
        int icblk = (k >> 9) & 3;
        int ocb = k >> 11;
        int oc = ocb * 16 + (l & 15);
        int ic = icblk * 32 + (l >> 4) * 8 + j;
        wfrag[k] = f2b(Wfu[oc * 128 + ic]);
    }
}

// Transpose x to px-major bf16: xb[bt][px][64 ic].
__global__ __launch_bounds__(256) void xconv_kernel(
    const float* __restrict__ x, unsigned short* __restrict__ xb)
{
    int bt = blockIdx.x >> 6;
    int px0 = (blockIdx.x & 63) * 64;
    __shared__ unsigned short sh[64 * 72];
    int tid = threadIdx.x;
    {
        int px_l = tid & 63;
        int ic4 = tid >> 6;
        const float* __restrict__ src = x + (size_t)bt * 64 * PX + px0 + px_l;
#pragma unroll
        for (int k = 0; k < 16; ++k) {
            int ic = ic4 * 16 + k;
            sh[px_l * 72 + ic] = f2b(src[(size_t)ic * PX]);
        }
    }
    __syncthreads();
    {
        int px_w = tid >> 2;
        int ch = tid & 3;
        uint4 v0 = *reinterpret_cast<const uint4*>(&sh[px_w * 72 + ch * 16]);
        uint4 v1 = *reinterpret_cast<const uint4*>(&sh[px_w * 72 + ch * 16 + 8]);
        unsigned short* dst = xb + ((size_t)bt * PX + px0 + px_w) * 64 + ch * 16;
        *reinterpret_cast<uint4*>(dst) = v0;
        *reinterpret_cast<uint4*>(dst + 8) = v1;
    }
}

// K1: implicit-GEMM conv via MFMA (R5 structure). Staging = pure uint4 copies.
// grid 512 (1-D): dirb = blockIdx&7 (XCD-local); rest: ocblk(4) x pxt(16).
__global__ __launch_bounds__(256, 2) void conv_mfma_kernel(
    const unsigned short* __restrict__ xb, const unsigned short* __restrict__ comb_t,
    const unsigned short* __restrict__ W2s,
    unsigned short* __restrict__ gatesb, float* __restrict__ gnstats, int s)
{
    const int dirb = blockIdx.x & 7;
    const int rest = blockIdx.x >> 3;
    const int dir = dirb >> 2, b = dirb & 3;
    const int ocblk = rest >> 4;
    const int pxt = rest & 15;
    const int py0 = (pxt >> 1) * 8;
    const int pxc0 = (pxt & 1) * 32;
    const int t = dir ? (15 - s) : s;
    const int prev_t = dir ? (t + 1) : (t - 1);

    __shared__ __align__(16) unsigned short Wl[9 * 64 * 32];   // 36,864 B
    __shared__ __align__(16) unsigned short in_s[340 * 32];    // 21,760 B
    __shared__ float red[8];

    const int tid = threadIdx.x;
    const int w = tid >> 6;
    const int l = tid & 63;
    const int l15 = l & 15;
    const int l4 = l >> 4;

    const unsigned short* __restrict__ xpx = xb + (size_t)(b * 16 + t) * PX * 64;
    const unsigned short* __restrict__ hpx = comb_t
        + (size_t)(prev_t * 4 + b) * PX * 128 + dir * 64;

    f32x4 acc[4][4];
#pragma unroll
    for (int i = 0; i < 4; ++i)
#pragma unroll
        for (int j = 0; j < 4; ++j)
            acc[i][j] = (f32x4){0.f, 0.f, 0.f, 0.f};

    for (int icblk = 0; icblk < 4; ++icblk) {
        __syncthreads();
        // ---- stage weights: straight 36,864-B copy (pre-swizzled)
        {
            const unsigned short* __restrict__ wsrc = W2s
                + ((size_t)((dir * 4 + ocblk) * 4 + icblk) * 9) * 2048;
#pragma unroll
            for (int it = 0; it < 9; ++it) {
                int e = tid + it * 256;
                *reinterpret_cast<uint4*>(&Wl[e * 8]) =
                    *reinterpret_cast<const uint4*>(wsrc + e * 8);
            }
        }
        // ---- stage input halo tile: 340 px x 32 ic (uint4 per lane)
        {
            const bool useh = icblk >= 2;
            const unsigned short* __restrict__ srcpx = useh
                ? (hpx + (icblk - 2) * 32) : (xpx + icblk * 32);
            const int rec = useh ? 128 : 64;
            const bool zero = useh && (s == 0);
#pragma unroll
            for (int it = 0; it < 6; ++it) {
                int idx = tid + it * 256;
                if (idx < 1360) {
                    int c = idx & 3;
                    int pl = idx >> 2;
                    int row = (pl * 241) >> 13;      // pl / 34
                    int col = pl - row * 34;
                    int gy = py0 - 1 + row;
                    int gx = pxc0 - 1 + col;
                    bool valid = ((unsigned)gy < 64u) && ((unsigned)gx < 64u) && !zero;
                    uint4 v = make_uint4(0u, 0u, 0u, 0u);
                    if (valid)
                        v = *reinterpret_cast<const uint4*>(
                            srcpx + (size_t)(gy * 64 + gx) * rec + c * 8);
                    int woff = pl * 32 + ((c ^ ((pl >> 1) & 3)) * 8);
                    *reinterpret_cast<uint4*>(&in_s[woff]) = v;
                }
            }
        }
        __syncthreads();

        // ---- 9 taps x 16 MFMA
#pragma unroll
        for (int tap = 0; tap < 9; ++tap) {
            const int dy = tap / 3, dx = tap % 3;
            bf16x8 av[4], bv[4];
#pragma unroll
            for (int mi = 0; mi < 4; ++mi) {
                int oc = mi * 16 + l15;
                int aoff = tap * 2048 + oc * 32 + ((l4 ^ ((oc >> 1) & 3)) * 8);
                av[mi] = *reinterpret_cast<const bf16x8*>(&Wl[aoff]);
            }
#pragma unroll
            for (int ni = 0; ni < 4; ++ni) {
                int nr = ni >> 1, nc = ni & 1;
                int pl = (2 * w + nr + dy) * 34 + nc * 16 + l15 + dx;
                int boff = pl * 32 + ((l4 ^ ((pl >> 1) & 3)) * 8);
                bv[ni] = *reinterpret_cast<const bf16x8*>(&in_s[boff]);
            }
#pragma unroll
            for (int mi = 0; mi < 4; ++mi)
#pragma unroll
                for (int ni = 0; ni < 4; ++ni)
                    acc[mi][ni] = __builtin_amdgcn_mfma_f32_16x16x32_bf16(
                        av[mi], bv[ni], acc[mi][ni], 0, 0, 0);
        }
    }

    // epilogue: write gates (bf16) + GN partial stats (fp32 from acc)
    float s1 = 0.f, s2 = 0.f;
    unsigned short* __restrict__ gbase = gatesb
        + ((size_t)dirb * 256 + (size_t)ocblk * 64) * PX;
#pragma unroll
    for (int mi = 0; mi < 4; ++mi)
#pragma unroll
        for (int ni = 0; ni < 4; ++ni) {
            int nr = ni >> 1, nc = ni & 1;
            int px = (py0 + 2 * w + nr) * 64 + pxc0 + nc * 16 + l15;
#pragma unroll
            for (int j = 0; j < 4; ++j) {
                float v = acc[mi][ni][j];
                int oc = mi * 16 + l4 * 4 + j;
                gbase[(size_t)oc * PX + px] = f2b(v);
                s1 += v;
                s2 += v * v;
            }
        }
    for (int off = 32; off; off >>= 1) {
        s1 += __shfl_down(s1, off);
        s2 += __shfl_down(s2, off);
    }
    if (l == 0) { red[w * 2] = s1; red[w * 2 + 1] = s2; }
    __syncthreads();
    if (tid == 0) {
        float a = red[0] + red[2] + red[4] + red[6];
        float q = red[1] + red[3] + red[5] + red[7];
        float* slot = gnstats + (((size_t)(s * 2 + dir) * 4 + b) * 4 + ocblk) * 2;
        atomicAdd(slot, a);
        atomicAdd(slot + 1, q);
    }
}

// K2: GN + activations + LSTM update; c stored bf16; h -> comb_t (bf16).
// grid 1024 (1-D): dirb = blockIdx&7 (XCD-local, same mapping as conv).
__global__ __launch_bounds__(256) void point_kernel2(
    const unsigned short* __restrict__ gatesb, const float* __restrict__ gnstats,
    const float* __restrict__ gnf_w, const float* __restrict__ gnf_b,
    const float* __restrict__ gnb_w, const float* __restrict__ gnb_b,
    unsigned short* __restrict__ cbuf, unsigned short* __restrict__ comb_t, int s)
{
    int dirb = blockIdx.x & 7;
    int idx = (blockIdx.x >> 3) * 256 + threadIdx.x;   // 0..32767 within dirb
    int pxl = idx & 7;
    int o8 = (idx >> 3) & 7;
    int pxh = idx >> 6;                                // 0..511
    int px = pxh * 8 + pxl;
    int dir = dirb >> 2, b = dirb & 3;

    __shared__ float gwl[256], gbl[256], mrs[8];
    int tid = threadIdx.x;
    {
        const float* __restrict__ gw = dir ? gnb_w : gnf_w;
        const float* __restrict__ gb = dir ? gnb_b : gnf_b;
        gwl[tid] = gw[tid];
        gbl[tid] = gb[tid];
    }
    if (tid < 4) {
        const float* slot = gnstats + ((size_t)(s * 2 + dir) * 4 + b) * 8 + tid * 2;
        const float invN = 1.0f / 262144.0f;
        float mean = slot[0] * invN;
        float var = slot[1] * invN - mean * mean;
        mrs[tid * 2] = mean;
        mrs[tid * 2 + 1] = rsqrtf(var + EPS);
    }
    __syncthreads();

    const unsigned short* __restrict__ gbase = gatesb + (size_t)dirb * 256 * PX + px;
    size_t cbase = ((size_t)dirb * 64 + o8 * 8) * PX + px;
    float m0 = mrs[0], r0 = mrs[1], m1 = mrs[2], r1 = mrs[3];
    float m2 = mrs[4], r2 = mrs[5], m3 = mrs[6], r3 = mrs[7];

    unsigned int packed[4];
#pragma unroll
    for (int cc = 0; cc < 8; ++cc) {
        int ch = o8 * 8 + cc;
        float g0 = b2f(gbase[(size_t)(ch) * PX]);
        float g1 = b2f(gbase[(size_t)(64 + ch) * PX]);
        float g2 = b2f(gbase[(size_t)(128 + ch) * PX]);
        float g3 = b2f(gbase[(size_t)(192 + ch) * PX]);
        float v0 = (g0 - m0) * r0 * gwl[ch] + gbl[ch];
        float v1 = (g1 - m1) * r1 * gwl[64 + ch] + gbl[64 + ch];
        float v2 = (g2 - m2) * r2 * gwl[128 + ch] + gbl[128 + ch];
        float v3 = (g3 - m3) * r3 * gwl[192 + ch] + gbl[192 + ch];
        float ig = rcpf(1.f + __expf(-v0));
        float fg = rcpf(1.f + __expf(-v1));
        float og = rcpf(1.f + __expf(-v2));
        float gg = 1.f - 2.f * rcpf(1.f + __expf(2.f * v3));
        float cold = b2f(cbuf[cbase + (size_t)cc * PX]);
        float cnew = fg * cold + ig * gg;
        float th = 1.f - 2.f * rcpf(1.f + __expf(2.f * cnew));
        float hnew = og * th;
        cbuf[cbase + (size_t)cc * PX] = f2b(cnew);
        unsigned int hb = (unsigned int)f2b(hnew);
        if (cc & 1) packed[cc >> 1] |= hb << 16;
        else        packed[cc >> 1] = hb;
    }
    int t = dir ? (15 - s) : s;
    size_t co = ((size_t)(t * 4 + b) * PX + px) * 128 + dir * 64 + o8 * 8;
    *reinterpret_cast<uint4*>(comb_t + co) =
        make_uint4(packed[0], packed[1], packed[2], packed[3]);
}

// K3: 1x1 fuse conv via MFMA; BN partial stats only.
__global__ __launch_bounds__(256) void fuse_stats2_kernel(
    const unsigned short* __restrict__ comb_t,
    const unsigned short* __restrict__ wfrag, float* __restrict__ bnparts)
{
    int n = blockIdx.x >> 4, pxb = blockIdx.x & 15;
    int tid = threadIdx.x;
    int w = tid >> 6, l = tid & 63;
    int l15 = l & 15, l4 = l >> 4;

    bf16x8 B[4][4];
#pragma unroll
    for (int ocb = 0; ocb < 4; ++ocb)
#pragma unroll
        for (int icblk = 0; icblk < 4; ++icblk)
            B[ocb][icblk] = *reinterpret_cast<const bf16x8*>(
                wfrag + (((ocb * 4 + icblk) * 64 + l) * 8));

    f32x4 acc[4][4];
#pragma unroll
    for (int i = 0; i < 4; ++i)
#pragma unroll
        for (int j = 0; j < 4; ++j)
            acc[i][j] = (f32x4){0.f, 0.f, 0.f, 0.f};

    int px0 = pxb * 256 + w * 64;
    const unsigned short* __restrict__ cb = comb_t + (size_t)n * PX * 128;
#pragma unroll
    for (int ps = 0; ps < 4; ++ps) {
        const unsigned short* ab = cb + (size_t)(px0 + ps * 16 + l15) * 128 + l4 * 8;
        bf16x8 A[4];
#pragma unroll
        for (int icblk = 0; icblk < 4; ++icblk)
            A[icblk] = *reinterpret_cast<const bf16x8*>(ab + icblk * 32);
#pragma unroll
        for (int icblk = 0; icblk < 4; ++icblk)
#pragma unroll
            for (int ocb = 0; ocb < 4; ++ocb)
                acc[ps][ocb] = __builtin_amdgcn_mfma_f32_16x16x32_bf16(
                    A[icblk], B[ocb][icblk], acc[ps][ocb], 0, 0, 0);
    }

    float s1[4] = {0, 0, 0, 0}, s2[4] = {0, 0, 0, 0};
#pragma unroll
    for (int ps = 0; ps < 4; ++ps)
#pragma unroll
        for (int ocb = 0; ocb < 4; ++ocb)
#pragma unroll
            for (int j = 0; j < 4; ++j) {
                float v = acc[ps][ocb][j];
                s1[ocb] += v;
                s2[ocb] += v * v;
            }
#pragma unroll
    for (int ocb = 0; ocb < 4; ++ocb) {
        s1[ocb] += __shfl_down(s1[ocb], 32);
        s1[ocb] += __shfl_down(s1[ocb], 16);
        s2[ocb] += __shfl_down(s2[ocb], 32);
        s2[ocb] += __shfl_down(s2[ocb], 16);
    }
    __shared__ float sred[4][4][16][2];
    if (l < 16)
#pragma unroll
        for (int ocb = 0; ocb < 4; ++ocb) {
            sred[w][ocb][l][0] = s1[ocb];
            sred[w][ocb][l][1] = s2[ocb];
        }
    __syncthreads();
    if (tid < 128) {
        int oc = tid >> 1, isq = tid & 1;
        float v = sred[0][oc >> 4][oc & 15][isq] + sred[1][oc >> 4][oc & 15][isq]
                + sred[2][oc >> 4][oc & 15][isq] + sred[3][oc >> 4][oc & 15][isq];
        atomicAdd(bnparts + (blockIdx.x & 7) * 128 + tid, v);
    }
}

// K4: recompute fuse MFMA, BN + ReLU, transposed store to out.
__global__ __launch_bounds__(256) void bn_apply2_kernel(
    const unsigned short* __restrict__ comb_t,
    const unsigned short* __restrict__ wfrag, const float* __restrict__ bnparts,
    const float* __restrict__ bn_w, const float* __restrict__ bn_b,
    float* __restrict__ out)
{
    int n = blockIdx.x >> 4, pxb = blockIdx.x & 15;
    int tid = threadIdx.x;
    int w = tid >> 6, l = tid & 63;
    int l15 = l & 15, l4 = l >> 4;

    __shared__ float sc[64], sh[64];
    if (tid < 64) {
        const float invN = 1.0f / 262144.0f;
        float S = 0.f, Q = 0.f;
#pragma unroll
        for (int p = 0; p < 8; ++p) {
            S += bnparts[p * 128 + tid * 2];
            Q += bnparts[p * 128 + tid * 2 + 1];
        }
        float mean = S * invN;
        float var = Q * invN - mean * mean;
        float scale = rsqrtf(var + EPS) * bn_w[tid];
        sc[tid] = scale;
        sh[tid] = bn_b[tid] - mean * scale;
    }

    bf16x8 B[4][4];
#pragma unroll
    for (int ocb = 0; ocb < 4; ++ocb)
#pragma unroll
        for (int icblk = 0; icblk < 4; ++icblk)
            B[ocb][icblk] = *reinterpret_cast<const bf16x8*>(
                wfrag + (((ocb * 4 + icblk) * 64 + l) * 8));
    __syncthreads();

    f32x4 acc[4][4];
#pragma unroll
    for (int i = 0; i < 4; ++i)
#pragma unroll
        for (int j = 0; j < 4; ++j)
            acc[i][j] = (f32x4){0.f, 0.f, 0.f, 0.f};

    int px0 = pxb * 256 + w * 64;
    const unsigned short* __restrict__ cb = comb_t + (size_t)n * PX * 128;
#pragma unroll
    for (int ps = 0; ps < 4; ++ps) {
        const unsigned short* ab = cb + (size_t)(px0 + ps * 16 + l15) * 128 + l4 * 8;
        bf16x8 A[4];
#pragma unroll
        for (int icblk = 0; icblk < 4; ++icblk)
            A[icblk] = *reinterpret_cast<const bf16x8*>(ab + icblk * 32);
#pragma unroll
        for (int icblk = 0; icblk < 4; ++icblk)
#pragma unroll
            for (int ocb = 0; ocb < 4; ++ocb)
                acc[ps][ocb] = __builtin_amdgcn_mfma_f32_16x16x32_bf16(
                    A[icblk], B[ocb][icblk], acc[ps][ocb], 0, 0, 0);
    }

    int t = n >> 2, bb = n & 3;
#pragma unroll
    for (int ps = 0; ps < 4; ++ps)
#pragma unroll
        for (int ocb = 0; ocb < 4; ++ocb) {
            int oc = ocb * 16 + l15;
            float scale = sc[oc], shift = sh[oc];
            float4 v;
            v.x = fmaxf(acc[ps][ocb][0] * scale + shift, 0.f);
            v.y = fmaxf(acc[ps][ocb][1] * scale + shift, 0.f);
            v.z = fmaxf(acc[ps][ocb][2] * scale + shift, 0.f);
            v.w = fmaxf(acc[ps][ocb][3] * scale + shift, 0.f);
            float* op = out + ((size_t)((bb * 16 + t) * 64 + oc)) * PX
                      + px0 + ps * 16 + l4 * 4;
            *reinterpret_cast<float4*>(op) = v;
        }
}

extern "C" void kernel_launch(void* const* d_in, const int* in_sizes, int n_in,
                              void* d_out, int out_size, void* d_ws, size_t ws_size,
                              hipStream_t stream) {
    const float* x     = (const float*)d_in[0];
    const float* Wf    = (const float*)d_in[1];
    const float* gnf_w = (const float*)d_in[2];
    const float* gnf_b = (const float*)d_in[3];
    const float* Wb    = (const float*)d_in[4];
    const float* gnb_w = (const float*)d_in[5];
    const float* gnb_b = (const float*)d_in[6];
    const float* Wfu   = (const float*)d_in[7];
    const float* bn_w  = (const float*)d_in[8];
    const float* bn_b  = (const float*)d_in[9];
    float* out = (float*)d_out;

    float* ws = (float*)d_ws;
    unsigned short* comb_t = (unsigned short*)ws;               // 16,777,216 f
    unsigned short* gatesb = (unsigned short*)(ws + 16777216);  //  4,194,304 f
    unsigned short* cbuf   = (unsigned short*)(ws + 20971520);  //  1,048,576 f
    float* gnstats = ws + 22020096;                             //      1,024 f
    float* bnparts = ws + 22021120;                             //      1,024 f
    unsigned short* W2s   = (unsigned short*)(ws + 22022144);   //    294,912 f
    unsigned short* wfrag = (unsigned short*)(ws + 22317056);   //      4,096 f
    unsigned short* xb    = (unsigned short*)(ws + 22321152);   //  8,388,608 f

    // zero c (bf16 zeros == 0x0000) + gn stats + bn partials (contiguous)
    hipMemsetAsync(cbuf, 0, (size_t)(1048576 + 2048) * 4, stream);

    pack_kernel<<<2336, 256, 0, stream>>>(Wf, Wb, Wfu, W2s, wfrag);
    xconv_kernel<<<4096, 256, 0, stream>>>(x, xb);

    for (int s = 0; s < 16; ++s) {
        conv_mfma_kernel<<<512, 256, 0, stream>>>(
            xb, comb_t, W2s, gatesb, gnstats, s);
        point_kernel2<<<1024, 256, 0, stream>>>(
            gatesb, gnstats, gnf_w, gnf_b, gnb_w, gnb_b, cbuf, comb_t, s);
    }
    fuse_stats2_kernel<<<1024, 256, 0, stream>>>(comb_t, wfrag, bnparts);
    bn_apply2_kernel<<<1024, 256, 0, stream>>>(comb_t, wfrag, bnparts, bn_w, bn_b, out);
}

// Round 17
// 596.170 us; speedup vs baseline: 2.0660x; 1.0181x over previous
//
#include <hip/hip_runtime.h>
#include <math.h>

#define PX 4096         // 64*64 spatial
#define EPS 1e-5f

typedef __attribute__((ext_vector_type(8))) __bf16 bf16x8;
typedef __attribute__((ext_vector_type(4))) float f32x4;

static __device__ __forceinline__ unsigned short f2b(float f) {
    unsigned int u = __float_as_uint(f);
    u += 0x7FFFu + ((u >> 16) & 1u);     // RTNE
    return (unsigned short)(u >> 16);
}
static __device__ __forceinline__ float b2f(unsigned short u) {
    return __uint_as_float((unsigned int)u << 16);
}
static __device__ __forceinline__ float rcpf(float x) {
    return __builtin_amdgcn_rcpf(x);
}

// ---------------------------------------------------------------------------
// ws layout (float units):
//   comb_t  bf16 [64 n][4096 px][128 ic]          16,777,216 f  @ 0
//   gatesb  bf16 [8 dirb][256 oc][4096 px]         4,194,304 f  @ 16,777,216
//   cbuf    bf16 [8 dirb][64 ch][4096]             1,048,576 f  @ 20,971,520
//   gnstat  f32  [16 s][2 dir][4 b][4 g][2]            1,024 f  @ 22,020,096
//   bnparts f32  [8 part][64 oc][2]                    1,024 f  @ 22,021,120
//   W2s     bf16 [dir][ocblk][icblk][tap][64][4][8] 294,912 f  @ 22,022,144
//   wfrag   bf16 [4 ocb][4 icblk][64 l][8 j]           4,096 f  @ 22,317,056
//   xb      bf16 [64 bt][4096 px][64 ic]            8,388,608 f @ 22,321,152
//
// R17 = R16 (606.9us) + async weight staging: the 36.9KB pre-swizzled weight
// copy uses __builtin_amdgcn_global_load_lds (width 16, linear LDS dest,
// wave-uniform base) instead of load->ds_write round-trips. Input staging
// unchanged (boundary divergence). Everything else identical to R16.
// ---------------------------------------------------------------------------

// Pack conv weights (pre-swizzled LDS image) + Wfu B-fragments, one launch.
__global__ __launch_bounds__(256) void pack_kernel(
    const float* __restrict__ Wf, const float* __restrict__ Wb,
    const float* __restrict__ Wfu,
    unsigned short* __restrict__ W2s, unsigned short* __restrict__ wfrag)
{
    int idx = blockIdx.x * 256 + threadIdx.x;
    if (idx < 589824) {
        int within = idx & 2047;
        int grp = idx >> 11;
        int oc = within >> 5;
        int slot = (within >> 3) & 3;
        int j = within & 7;
        int tap = grp % 9;
        int rest = grp / 9;
        int icblk = rest & 3;
        int ocblk = (rest >> 2) & 3;
        int dir = rest >> 4;
        int c = slot ^ ((oc >> 1) & 3);
        int ic = icblk * 32 + c * 8 + j;
        int OC = ocblk * 64 + oc;
        const float* __restrict__ W = dir ? Wb : Wf;
        W2s[idx] = f2b(W[((size_t)OC * 128 + ic) * 9 + tap]);
    } else if (idx < 589824 + 8192) {
        int k = idx - 589824;
        int j = k & 7;
        int l = (k >> 3) & 63;
        int icblk = (k >> 9) & 3;
        int ocb = k >> 11;
        int oc = ocb * 16 + (l & 15);
        int ic = icblk * 32 + (l >> 4) * 8 + j;
        wfrag[k] = f2b(Wfu[oc * 128 + ic]);
    }
}

// Transpose x to px-major bf16: xb[bt][px][64 ic].
__global__ __launch_bounds__(256) void xconv_kernel(
    const float* __restrict__ x, unsigned short* __restrict__ xb)
{
    int bt = blockIdx.x >> 6;
    int px0 = (blockIdx.x & 63) * 64;
    __shared__ unsigned short sh[64 * 72];
    int tid = threadIdx.x;
    {
        int px_l = tid & 63;
        int ic4 = tid >> 6;
        const float* __restrict__ src = x + (size_t)bt * 64 * PX + px0 + px_l;
#pragma unroll
        for (int k = 0; k < 16; ++k) {
            int ic = ic4 * 16 + k;
            sh[px_l * 72 + ic] = f2b(src[(size_t)ic * PX]);
        }
    }
    __syncthreads();
    {
        int px_w = tid >> 2;
        int ch = tid & 3;
        uint4 v0 = *reinterpret_cast<const uint4*>(&sh[px_w * 72 + ch * 16]);
        uint4 v1 = *reinterpret_cast<const uint4*>(&sh[px_w * 72 + ch * 16 + 8]);
        unsigned short* dst = xb + ((size_t)bt * PX + px0 + px_w) * 64 + ch * 16;
        *reinterpret_cast<uint4*>(dst) = v0;
        *reinterpret_cast<uint4*>(dst + 8) = v1;
    }
}

// K1: implicit-GEMM conv via MFMA. Weight staging = async global->LDS
// (global_load_lds dwordx4); input staging = uint4 copies (as R16).
// grid 512 (1-D): dirb = blockIdx&7 (XCD-local); rest: ocblk(4) x pxt(16).
__global__ __launch_bounds__(256, 2) void conv_mfma_kernel(
    const unsigned short* __restrict__ xb, const unsigned short* __restrict__ comb_t,
    const unsigned short* __restrict__ W2s,
    unsigned short* __restrict__ gatesb, float* __restrict__ gnstats, int s)
{
    const int dirb = blockIdx.x & 7;
    const int rest = blockIdx.x >> 3;
    const int dir = dirb >> 2, b = dirb & 3;
    const int ocblk = rest >> 4;
    const int pxt = rest & 15;
    const int py0 = (pxt >> 1) * 8;
    const int pxc0 = (pxt & 1) * 32;
    const int t = dir ? (15 - s) : s;
    const int prev_t = dir ? (t + 1) : (t - 1);

    __shared__ __align__(16) unsigned short Wl[9 * 64 * 32];   // 36,864 B
    __shared__ __align__(16) unsigned short in_s[340 * 32];    // 21,760 B
    __shared__ float red[8];

    const int tid = threadIdx.x;
    const int w = tid >> 6;
    const int l = tid & 63;
    const int l15 = l & 15;
    const int l4 = l >> 4;
    const int wb = tid & ~63;            // wave-uniform lane-0 thread index

    const unsigned short* __restrict__ xpx = xb + (size_t)(b * 16 + t) * PX * 64;
    const unsigned short* __restrict__ hpx = comb_t
        + (size_t)(prev_t * 4 + b) * PX * 128 + dir * 64;

    f32x4 acc[4][4];
#pragma unroll
    for (int i = 0; i < 4; ++i)
#pragma unroll
        for (int j = 0; j < 4; ++j)
            acc[i][j] = (f32x4){0.f, 0.f, 0.f, 0.f};

    for (int icblk = 0; icblk < 4; ++icblk) {
        __syncthreads();
        // ---- stage weights: async global->LDS, 16B/lane x 9 issues.
        // LDS dest passed as wave-uniform base; HW writes lane l at +l*16.
        {
            const unsigned short* __restrict__ wsrc = W2s
                + ((size_t)((dir * 4 + ocblk) * 4 + icblk) * 9) * 2048;
#pragma unroll
            for (int it = 0; it < 9; ++it) {
                __builtin_amdgcn_global_load_lds(
                    (const __attribute__((address_space(1))) void*)
                        (wsrc + (size_t)(tid + it * 256) * 8),
                    (__attribute__((address_space(3))) void*)
                        (&Wl[(wb + it * 256) * 8]),
                    16, 0, 0);
            }
        }
        // ---- stage input halo tile: 340 px x 32 ic (uint4 per lane)
        {
            const bool useh = icblk >= 2;
            const unsigned short* __restrict__ srcpx = useh
                ? (hpx + (icblk - 2) * 32) : (xpx + icblk * 32);
            const int rec = useh ? 128 : 64;
            const bool zero = useh && (s == 0);
#pragma unroll
            for (int it = 0; it < 6; ++it) {
                int idx = tid + it * 256;
                if (idx < 1360) {
                    int c = idx & 3;
                    int pl = idx >> 2;
                    int row = (pl * 241) >> 13;      // pl / 34
                    int col = pl - row * 34;
                    int gy = py0 - 1 + row;
                    int gx = pxc0 - 1 + col;
                    bool valid = ((unsigned)gy < 64u) && ((unsigned)gx < 64u) && !zero;
                    uint4 v = make_uint4(0u, 0u, 0u, 0u);
                    if (valid)
                        v = *reinterpret_cast<const uint4*>(
                            srcpx + (size_t)(gy * 64 + gx) * rec + c * 8);
                    int woff = pl * 32 + ((c ^ ((pl >> 1) & 3)) * 8);
                    *reinterpret_cast<uint4*>(&in_s[woff]) = v;
                }
            }
        }
        __syncthreads();

        // ---- 9 taps x 16 MFMA
#pragma unroll
        for (int tap = 0; tap < 9; ++tap) {
            const int dy = tap / 3, dx = tap % 3;
            bf16x8 av[4], bv[4];
#pragma unroll
            for (int mi = 0; mi < 4; ++mi) {
                int oc = mi * 16 + l15;
                int aoff = tap * 2048 + oc * 32 + ((l4 ^ ((oc >> 1) & 3)) * 8);
                av[mi] = *reinterpret_cast<const bf16x8*>(&Wl[aoff]);
            }
#pragma unroll
            for (int ni = 0; ni < 4; ++ni) {
                int nr = ni >> 1, nc = ni & 1;
                int pl = (2 * w + nr + dy) * 34 + nc * 16 + l15 + dx;
                int boff = pl * 32 + ((l4 ^ ((pl >> 1) & 3)) * 8);
                bv[ni] = *reinterpret_cast<const bf16x8*>(&in_s[boff]);
            }
#pragma unroll
            for (int mi = 0; mi < 4; ++mi)
#pragma unroll
                for (int ni = 0; ni < 4; ++ni)
                    acc[mi][ni] = __builtin_amdgcn_mfma_f32_16x16x32_bf16(
                        av[mi], bv[ni], acc[mi][ni], 0, 0, 0);
        }
    }

    // epilogue: write gates (bf16) + GN partial stats (fp32 from acc)
    float s1 = 0.f, s2 = 0.f;
    unsigned short* __restrict__ gbase = gatesb
        + ((size_t)dirb * 256 + (size_t)ocblk * 64) * PX;
#pragma unroll
    for (int mi = 0; mi < 4; ++mi)
#pragma unroll
        for (int ni = 0; ni < 4; ++ni) {
            int nr = ni >> 1, nc = ni & 1;
            int px = (py0 + 2 * w + nr) * 64 + pxc0 + nc * 16 + l15;
#pragma unroll
            for (int j = 0; j < 4; ++j) {
                float v = acc[mi][ni][j];
                int oc = mi * 16 + l4 * 4 + j;
                gbase[(size_t)oc * PX + px] = f2b(v);
                s1 += v;
                s2 += v * v;
            }
        }
    for (int off = 32; off; off >>= 1) {
        s1 += __shfl_down(s1, off);
        s2 += __shfl_down(s2, off);
    }
    if (l == 0) { red[w * 2] = s1; red[w * 2 + 1] = s2; }
    __syncthreads();
    if (tid == 0) {
        float a = red[0] + red[2] + red[4] + red[6];
        float q = red[1] + red[3] + red[5] + red[7];
        float* slot = gnstats + (((size_t)(s * 2 + dir) * 4 + b) * 4 + ocblk) * 2;
        atomicAdd(slot, a);
        atomicAdd(slot + 1, q);
    }
}

// K2: GN + activations + LSTM update; c stored bf16; h -> comb_t (bf16).
// grid 1024 (1-D): dirb = blockIdx&7 (XCD-local, same mapping as conv).
__global__ __launch_bounds__(256) void point_kernel2(
    const unsigned short* __restrict__ gatesb, const float* __restrict__ gnstats,
    const float* __restrict__ gnf_w, const float* __restrict__ gnf_b,
    const float* __restrict__ gnb_w, const float* __restrict__ gnb_b,
    unsigned short* __restrict__ cbuf, unsigned short* __restrict__ comb_t, int s)
{
    int dirb = blockIdx.x & 7;
    int idx = (blockIdx.x >> 3) * 256 + threadIdx.x;   // 0..32767 within dirb
    int pxl = idx & 7;
    int o8 = (idx >> 3) & 7;
    int pxh = idx >> 6;                                // 0..511
    int px = pxh * 8 + pxl;
    int dir = dirb >> 2, b = dirb & 3;

    __shared__ float gwl[256], gbl[256], mrs[8];
    int tid = threadIdx.x;
    {
        const float* __restrict__ gw = dir ? gnb_w : gnf_w;
        const float* __restrict__ gb = dir ? gnb_b : gnf_b;
        gwl[tid] = gw[tid];
        gbl[tid] = gb[tid];
    }
    if (tid < 4) {
        const float* slot = gnstats + ((size_t)(s * 2 + dir) * 4 + b) * 8 + tid * 2;
        const float invN = 1.0f / 262144.0f;
        float mean = slot[0] * invN;
        float var = slot[1] * invN - mean * mean;
        mrs[tid * 2] = mean;
        mrs[tid * 2 + 1] = rsqrtf(var + EPS);
    }
    __syncthreads();

    const unsigned short* __restrict__ gbase = gatesb + (size_t)dirb * 256 * PX + px;
    size_t cbase = ((size_t)dirb * 64 + o8 * 8) * PX + px;
    float m0 = mrs[0], r0 = mrs[1], m1 = mrs[2], r1 = mrs[3];
    float m2 = mrs[4], r2 = mrs[5], m3 = mrs[6], r3 = mrs[7];

    unsigned int packed[4];
#pragma unroll
    for (int cc = 0; cc < 8; ++cc) {
        int ch = o8 * 8 + cc;
        float g0 = b2f(gbase[(size_t)(ch) * PX]);
        float g1 = b2f(gbase[(size_t)(64 + ch) * PX]);
        float g2 = b2f(gbase[(size_t)(128 + ch) * PX]);
        float g3 = b2f(gbase[(size_t)(192 + ch) * PX]);
        float v0 = (g0 - m0) * r0 * gwl[ch] + gbl[ch];
        float v1 = (g1 - m1) * r1 * gwl[64 + ch] + gbl[64 + ch];
        float v2 = (g2 - m2) * r2 * gwl[128 + ch] + gbl[128 + ch];
        float v3 = (g3 - m3) * r3 * gwl[192 + ch] + gbl[192 + ch];
        float ig = rcpf(1.f + __expf(-v0));
        float fg = rcpf(1.f + __expf(-v1));
        float og = rcpf(1.f + __expf(-v2));
        float gg = 1.f - 2.f * rcpf(1.f + __expf(2.f * v3));
        float cold = b2f(cbuf[cbase + (size_t)cc * PX]);
        float cnew = fg * cold + ig * gg;
        float th = 1.f - 2.f * rcpf(1.f + __expf(2.f * cnew));
        float hnew = og * th;
        cbuf[cbase + (size_t)cc * PX] = f2b(cnew);
        unsigned int hb = (unsigned int)f2b(hnew);
        if (cc & 1) packed[cc >> 1] |= hb << 16;
        else        packed[cc >> 1] = hb;
    }
    int t = dir ? (15 - s) : s;
    size_t co = ((size_t)(t * 4 + b) * PX + px) * 128 + dir * 64 + o8 * 8;
    *reinterpret_cast<uint4*>(comb_t + co) =
        make_uint4(packed[0], packed[1], packed[2], packed[3]);
}

// K3: 1x1 fuse conv via MFMA; BN partial stats only.
__global__ __launch_bounds__(256) void fuse_stats2_kernel(
    const unsigned short* __restrict__ comb_t,
    const unsigned short* __restrict__ wfrag, float* __restrict__ bnparts)
{
    int n = blockIdx.x >> 4, pxb = blockIdx.x & 15;
    int tid = threadIdx.x;
    int w = tid >> 6, l = tid & 63;
    int l15 = l & 15, l4 = l >> 4;

    bf16x8 B[4][4];
#pragma unroll
    for (int ocb = 0; ocb < 4; ++ocb)
#pragma unroll
        for (int icblk = 0; icblk < 4; ++icblk)
            B[ocb][icblk] = *reinterpret_cast<const bf16x8*>(
                wfrag + (((ocb * 4 + icblk) * 64 + l) * 8));

    f32x4 acc[4][4];
#pragma unroll
    for (int i = 0; i < 4; ++i)
#pragma unroll
        for (int j = 0; j < 4; ++j)
            acc[i][j] = (f32x4){0.f, 0.f, 0.f, 0.f};

    int px0 = pxb * 256 + w * 64;
    const unsigned short* __restrict__ cb = comb_t + (size_t)n * PX * 128;
#pragma unroll
    for (int ps = 0; ps < 4; ++ps) {
        const unsigned short* ab = cb + (size_t)(px0 + ps * 16 + l15) * 128 + l4 * 8;
        bf16x8 A[4];
#pragma unroll
        for (int icblk = 0; icblk < 4; ++icblk)
            A[icblk] = *reinterpret_cast<const bf16x8*>(ab + icblk * 32);
#pragma unroll
        for (int icblk = 0; icblk < 4; ++icblk)
#pragma unroll
            for (int ocb = 0; ocb < 4; ++ocb)
                acc[ps][ocb] = __builtin_amdgcn_mfma_f32_16x16x32_bf16(
                    A[icblk], B[ocb][icblk], acc[ps][ocb], 0, 0, 0);
    }

    float s1[4] = {0, 0, 0, 0}, s2[4] = {0, 0, 0, 0};
#pragma unroll
    for (int ps = 0; ps < 4; ++ps)
#pragma unroll
        for (int ocb = 0; ocb < 4; ++ocb)
#pragma unroll
            for (int j = 0; j < 4; ++j) {
                float v = acc[ps][ocb][j];
                s1[ocb] += v;
                s2[ocb] += v * v;
            }
#pragma unroll
    for (int ocb = 0; ocb < 4; ++ocb) {
        s1[ocb] += __shfl_down(s1[ocb], 32);
        s1[ocb] += __shfl_down(s1[ocb], 16);
        s2[ocb] += __shfl_down(s2[ocb], 32);
        s2[ocb] += __shfl_down(s2[ocb], 16);
    }
    __shared__ float sred[4][4][16][2];
    if (l < 16)
#pragma unroll
        for (int ocb = 0; ocb < 4; ++ocb) {
            sred[w][ocb][l][0] = s1[ocb];
            sred[w][ocb][l][1] = s2[ocb];
        }
    __syncthreads();
    if (tid < 128) {
        int oc = tid >> 1, isq = tid & 1;
        float v = sred[0][oc >> 4][oc & 15][isq] + sred[1][oc >> 4][oc & 15][isq]
                + sred[2][oc >> 4][oc & 15][isq] + sred[3][oc >> 4][oc & 15][isq];
        atomicAdd(bnparts + (blockIdx.x & 7) * 128 + tid, v);
    }
}

// K4: recompute fuse MFMA, BN + ReLU, transposed store to out.
__global__ __launch_bounds__(256) void bn_apply2_kernel(
    const unsigned short* __restrict__ comb_t,
    const unsigned short* __restrict__ wfrag, const float* __restrict__ bnparts,
    const float* __restrict__ bn_w, const float* __restrict__ bn_b,
    float* __restrict__ out)
{
    int n = blockIdx.x >> 4, pxb = blockIdx.x & 15;
    int tid = threadIdx.x;
    int w = tid >> 6, l = tid & 63;
    int l15 = l & 15, l4 = l >> 4;

    __shared__ float sc[64], sh[64];
    if (tid < 64) {
        const float invN = 1.0f / 262144.0f;
        float S = 0.f, Q = 0.f;
#pragma unroll
        for (int p = 0; p < 8; ++p) {
            S += bnparts[p * 128 + tid * 2];
            Q += bnparts[p * 128 + tid * 2 + 1];
        }
        float mean = S * invN;
        float var = Q * invN - mean * mean;
        float scale = rsqrtf(var + EPS) * bn_w[tid];
        sc[tid] = scale;
        sh[tid] = bn_b[tid] - mean * scale;
    }

    bf16x8 B[4][4];
#pragma unroll
    for (int ocb = 0; ocb < 4; ++ocb)
#pragma unroll
        for (int icblk = 0; icblk < 4; ++icblk)
            B[ocb][icblk] = *reinterpret_cast<const bf16x8*>(
                wfrag + (((ocb * 4 + icblk) * 64 + l) * 8));
    __syncthreads();

    f32x4 acc[4][4];
#pragma unroll
    for (int i = 0; i < 4; ++i)
#pragma unroll
        for (int j = 0; j < 4; ++j)
            acc[i][j] = (f32x4){0.f, 0.f, 0.f, 0.f};

    int px0 = pxb * 256 + w * 64;
    const unsigned short* __restrict__ cb = comb_t + (size_t)n * PX * 128;
#pragma unroll
    for (int ps = 0; ps < 4; ++ps) {
        const unsigned short* ab = cb + (size_t)(px0 + ps * 16 + l15) * 128 + l4 * 8;
        bf16x8 A[4];
#pragma unroll
        for (int icblk = 0; icblk < 4; ++icblk)
            A[icblk] = *reinterpret_cast<const bf16x8*>(ab + icblk * 32);
#pragma unroll
        for (int icblk = 0; icblk < 4; ++icblk)
#pragma unroll
            for (int ocb = 0; ocb < 4; ++ocb)
                acc[ps][ocb] = __builtin_amdgcn_mfma_f32_16x16x32_bf16(
                    A[icblk], B[ocb][icblk], acc[ps][ocb], 0, 0, 0);
    }

    int t = n >> 2, bb = n & 3;
#pragma unroll
    for (int ps = 0; ps < 4; ++ps)
#pragma unroll
        for (int ocb = 0; ocb < 4; ++ocb) {
            int oc = ocb * 16 + l15;
            float scale = sc[oc], shift = sh[oc];
            float4 v;
            v.x = fmaxf(acc[ps][ocb][0] * scale + shift, 0.f);
            v.y = fmaxf(acc[ps][ocb][1] * scale + shift, 0.f);
            v.z = fmaxf(acc[ps][ocb][2] * scale + shift, 0.f);
            v.w = fmaxf(acc[ps][ocb][3] * scale + shift, 0.f);
            float* op = out + ((size_t)((bb * 16 + t) * 64 + oc)) * PX
                      + px0 + ps * 16 + l4 * 4;
            *reinterpret_cast<float4*>(op) = v;
        }
}

extern "C" void kernel_launch(void* const* d_in, const int* in_sizes, int n_in,
                              void* d_out, int out_size, void* d_ws, size_t ws_size,
                              hipStream_t stream) {
    const float* x     = (const float*)d_in[0];
    const float* Wf    = (const float*)d_in[1];
    const float* gnf_w = (const float*)d_in[2];
    const float* gnf_b = (const float*)d_in[3];
    const float* Wb    = (const float*)d_in[4];
    const float* gnb_w = (const float*)d_in[5];
    const float* gnb_b = (const float*)d_in[6];
    const float* Wfu   = (const float*)d_in[7];
    const float* bn_w  = (const float*)d_in[8];
    const float* bn_b  = (const float*)d_in[9];
    float* out = (float*)d_out;

    float* ws = (float*)d_ws;
    unsigned short* comb_t = (unsigned short*)ws;               // 16,777,216 f
    unsigned short* gatesb = (unsigned short*)(ws + 16777216);  //  4,194,304 f
    unsigned short* cbuf   = (unsigned short*)(ws + 20971520);  //  1,048,576 f
    float* gnstats = ws + 22020096;                             //      1,024 f
    float* bnparts = ws + 22021120;                             //      1,024 f
    unsigned short* W2s   = (unsigned short*)(ws + 22022144);   //    294,912 f
    unsigned short* wfrag = (unsigned short*)(ws + 22317056);   //      4,096 f
    unsigned short* xb    = (unsigned short*)(ws + 22321152);   //  8,388,608 f

    // zero c (bf16 zeros == 0x0000) + gn stats + bn partials (contiguous)
    hipMemsetAsync(cbuf, 0, (size_t)(1048576 + 2048) * 4, stream);

    pack_kernel<<<2336, 256, 0, stream>>>(Wf, Wb, Wfu, W2s, wfrag);
    xconv_kernel<<<4096, 256, 0, stream>>>(x, xb);

    for (int s = 0; s < 16; ++s) {
        conv_mfma_kernel<<<512, 256, 0, stream>>>(
            xb, comb_t, W2s, gatesb, gnstats, s);
        point_kernel2<<<1024, 256, 0, stream>>>(
            gatesb, gnstats, gnf_w, gnf_b, gnb_w, gnb_b, cbuf, comb_t, s);
    }
    fuse_stats2_kernel<<<1024, 256, 0, stream>>>(comb_t, wfrag, bnparts);
    bn_apply2_kernel<<<1024, 256, 0, stream>>>(comb_t, wfrag, bnparts, bn_w, bn_b, out);
}

// Round 18
// 568.894 us; speedup vs baseline: 2.1651x; 1.0479x over previous
//
#include <hip/hip_runtime.h>
#include <math.h>

#define PX 4096         // 64*64 spatial
#define EPS 1e-5f

typedef __attribute__((ext_vector_type(8))) __bf16 bf16x8;
typedef __attribute__((ext_vector_type(4))) float f32x4;

static __device__ __forceinline__ unsigned short f2b(float f) {
    unsigned int u = __float_as_uint(f);
    u += 0x7FFFu + ((u >> 16) & 1u);     // RTNE
    return (unsigned short)(u >> 16);
}
static __device__ __forceinline__ float b2f(unsigned short u) {
    return __uint_as_float((unsigned int)u << 16);
}
static __device__ __forceinline__ float rcpf(float x) {
    return __builtin_amdgcn_rcpf(x);
}

// ---------------------------------------------------------------------------
// ws layout (float units):
//   comb_t  bf16 [64 n][4096 px][128 ic]          16,777,216 f  @ 0
//   gatesb  bf16 [8 dirb][256 oc][4096 px]         4,194,304 f  @ 16,777,216
//   cbuf    bf16 [8 dirb][64 ch][4096]             1,048,576 f  @ 20,971,520
//   gnstat  f32  [16 s][2 dir][4 b][4 g][2]            1,024 f  @ 22,020,096
//   bnparts f32  [8 part][64 oc][2]                    1,024 f  @ 22,021,120
//   W2s     bf16 [dir][ocblk][icblk][tap][64][4][8] 294,912 f  @ 22,022,144
//   wfrag   bf16 [4 ocb][4 icblk][64 l][8 j]           4,096 f  @ 22,317,056
//   xb      bf16 [64 bt][4096 px][64 ic]            8,388,608 f @ 22,321,152
//
// R18 = R17 (596us) + T14 input-stage split: input loads for icblk+1 are
// ISSUED right after the drain barrier (so they fly across the whole MFMA
// phase; issuing before a barrier is useless - vmcnt(0) drain), ds_write
// happens next phase. Weights stay async global_load_lds (R17). Occupancy
// is LDS-capped (2 blocks/CU) so the +24 VGPR for in-flight loads is free.
// ---------------------------------------------------------------------------

// Pack conv weights (pre-swizzled LDS image) + Wfu B-fragments, one launch.
__global__ __launch_bounds__(256) void pack_kernel(
    const float* __restrict__ Wf, const float* __restrict__ Wb,
    const float* __restrict__ Wfu,
    unsigned short* __restrict__ W2s, unsigned short* __restrict__ wfrag)
{
    int idx = blockIdx.x * 256 + threadIdx.x;
    if (idx < 589824) {
        int within = idx & 2047;
        int grp = idx >> 11;
        int oc = within >> 5;
        int slot = (within >> 3) & 3;
        int j = within & 7;
        int tap = grp % 9;
        int rest = grp / 9;
        int icblk = rest & 3;
        int ocblk = (rest >> 2) & 3;
        int dir = rest >> 4;
        int c = slot ^ ((oc >> 1) & 3);
        int ic = icblk * 32 + c * 8 + j;
        int OC = ocblk * 64 + oc;
        const float* __restrict__ W = dir ? Wb : Wf;
        W2s[idx] = f2b(W[((size_t)OC * 128 + ic) * 9 + tap]);
    } else if (idx < 589824 + 8192) {
        int k = idx - 589824;
        int j = k & 7;
        int l = (k >> 3) & 63;
        int icblk = (k >> 9) & 3;
        int ocb = k >> 11;
        int oc = ocb * 16 + (l & 15);
        int ic = icblk * 32 + (l >> 4) * 8 + j;
        wfrag[k] = f2b(Wfu[oc * 128 + ic]);
    }
}

// Transpose x to px-major bf16: xb[bt][px][64 ic].
__global__ __launch_bounds__(256) void xconv_kernel(
    const float* __restrict__ x, unsigned short* __restrict__ xb)
{
    int bt = blockIdx.x >> 6;
    int px0 = (blockIdx.x & 63) * 64;
    __shared__ unsigned short sh[64 * 72];
    int tid = threadIdx.x;
    {
        int px_l = tid & 63;
        int ic4 = tid >> 6;
        const float* __restrict__ src = x + (size_t)bt * 64 * PX + px0 + px_l;
#pragma unroll
        for (int k = 0; k < 16; ++k) {
            int ic = ic4 * 16 + k;
            sh[px_l * 72 + ic] = f2b(src[(size_t)ic * PX]);
        }
    }
    __syncthreads();
    {
        int px_w = tid >> 2;
        int ch = tid & 3;
        uint4 v0 = *reinterpret_cast<const uint4*>(&sh[px_w * 72 + ch * 16]);
        uint4 v1 = *reinterpret_cast<const uint4*>(&sh[px_w * 72 + ch * 16 + 8]);
        unsigned short* dst = xb + ((size_t)bt * PX + px0 + px_w) * 64 + ch * 16;
        *reinterpret_cast<uint4*>(dst) = v0;
        *reinterpret_cast<uint4*>(dst + 8) = v1;
    }
}

// K1: implicit-GEMM conv via MFMA. Weights: async global->LDS. Input: T14
// split (issue-after-barrier / write-next-phase).
// grid 512 (1-D): dirb = blockIdx&7 (XCD-local); rest: ocblk(4) x pxt(16).
__global__ __launch_bounds__(256, 2) void conv_mfma_kernel(
    const unsigned short* __restrict__ xb, const unsigned short* __restrict__ comb_t,
    const unsigned short* __restrict__ W2s,
    unsigned short* __restrict__ gatesb, float* __restrict__ gnstats, int s)
{
    const int dirb = blockIdx.x & 7;
    const int rest = blockIdx.x >> 3;
    const int dir = dirb >> 2, b = dirb & 3;
    const int ocblk = rest >> 4;
    const int pxt = rest & 15;
    const int py0 = (pxt >> 1) * 8;
    const int pxc0 = (pxt & 1) * 32;
    const int t = dir ? (15 - s) : s;
    const int prev_t = dir ? (t + 1) : (t - 1);

    __shared__ __align__(16) unsigned short Wl[9 * 64 * 32];   // 36,864 B
    __shared__ __align__(16) unsigned short in_s[340 * 32];    // 21,760 B
    __shared__ float red[8];

    const int tid = threadIdx.x;
    const int w = tid >> 6;
    const int l = tid & 63;
    const int l15 = l & 15;
    const int l4 = l >> 4;
    const int wb = tid & ~63;            // wave-uniform lane-0 thread index

    const unsigned short* __restrict__ xpx = xb + (size_t)(b * 16 + t) * PX * 64;
    const unsigned short* __restrict__ hpx = comb_t
        + (size_t)(prev_t * 4 + b) * PX * 128 + dir * 64;

    // staging address precompute (per-lane, reused each phase)
    int sg_px[6];      // global pixel index, -1 if out of tile
#pragma unroll
    for (int it = 0; it < 6; ++it) {
        int idx = tid + it * 256;
        int pl = idx >> 2;
        int row = (pl * 241) >> 13;          // pl / 34
        int col = pl - row * 34;
        int gy = py0 - 1 + row;
        int gx = pxc0 - 1 + col;
        bool valid = (idx < 1360) && ((unsigned)gy < 64u) && ((unsigned)gx < 64u);
        sg_px[it] = valid ? (gy * 64 + gx) : -1;
    }

    f32x4 acc[4][4];
#pragma unroll
    for (int i = 0; i < 4; ++i)
#pragma unroll
        for (int j = 0; j < 4; ++j)
            acc[i][j] = (f32x4){0.f, 0.f, 0.f, 0.f};

    uint4 sreg[6];
    // issue input loads for icblk into sreg (no LDS write)
    auto stage_load = [&](int icblk) {
        const bool useh = icblk >= 2;
        const unsigned short* __restrict__ srcpx = useh
            ? (hpx + (icblk - 2) * 32) : (xpx + icblk * 32);
        const int rec = useh ? 128 : 64;
        const bool zero = useh && (s == 0);
        const int c = tid & 3;
#pragma unroll
        for (int it = 0; it < 6; ++it) {
            uint4 v = make_uint4(0u, 0u, 0u, 0u);
            if (sg_px[it] >= 0 && !zero)
                v = *reinterpret_cast<const uint4*>(
                    srcpx + (size_t)sg_px[it] * rec + c * 8);
            sreg[it] = v;
        }
    };
    // write sreg into in_s (swizzled)
    auto stage_write = [&]() {
#pragma unroll
        for (int it = 0; it < 6; ++it) {
            int idx = tid + it * 256;
            if (idx < 1360) {
                int c = idx & 3;
                int pl = idx >> 2;
                int woff = pl * 32 + ((c ^ ((pl >> 1) & 3)) * 8);
                *reinterpret_cast<uint4*>(&in_s[woff]) = sreg[it];
            }
        }
    };
    // async weight stage: 16B/lane x 9, linear LDS dest (wave-uniform base)
    auto issueW = [&](int icblk) {
        const unsigned short* __restrict__ wsrc = W2s
            + ((size_t)((dir * 4 + ocblk) * 4 + icblk) * 9) * 2048;
#pragma unroll
        for (int it = 0; it < 9; ++it) {
            __builtin_amdgcn_global_load_lds(
                (const __attribute__((address_space(1))) void*)
                    (wsrc + (size_t)(tid + it * 256) * 8),
                (__attribute__((address_space(3))) void*)
                    (&Wl[(wb + it * 256) * 8]),
                16, 0, 0);
        }
    };

    stage_load(0);                       // prologue: input loads in flight

    for (int icblk = 0; icblk < 4; ++icblk) {
        __syncthreads();                 // A: prior compute done with Wl/in_s
        issueW(icblk);
        stage_write();                   // waits sreg deps, writes LDS
        __syncthreads();                 // B: drain weights + lgkm writes
        if (icblk < 3) stage_load(icblk + 1);  // fly across the MFMA phase

#pragma unroll
        for (int tap = 0; tap < 9; ++tap) {
            const int dy = tap / 3, dx = tap % 3;
            bf16x8 av[4], bv[4];
#pragma unroll
            for (int mi = 0; mi < 4; ++mi) {
                int oc = mi * 16 + l15;
                int aoff = tap * 2048 + oc * 32 + ((l4 ^ ((oc >> 1) & 3)) * 8);
                av[mi] = *reinterpret_cast<const bf16x8*>(&Wl[aoff]);
            }
#pragma unroll
            for (int ni = 0; ni < 4; ++ni) {
                int nr = ni >> 1, nc = ni & 1;
                int pl = (2 * w + nr + dy) * 34 + nc * 16 + l15 + dx;
                int boff = pl * 32 + ((l4 ^ ((pl >> 1) & 3)) * 8);
                bv[ni] = *reinterpret_cast<const bf16x8*>(&in_s[boff]);
            }
#pragma unroll
            for (int mi = 0; mi < 4; ++mi)
#pragma unroll
                for (int ni = 0; ni < 4; ++ni)
                    acc[mi][ni] = __builtin_amdgcn_mfma_f32_16x16x32_bf16(
                        av[mi], bv[ni], acc[mi][ni], 0, 0, 0);
        }
    }

    // epilogue: write gates (bf16) + GN partial stats (fp32 from acc)
    float s1 = 0.f, s2 = 0.f;
    unsigned short* __restrict__ gbase = gatesb
        + ((size_t)dirb * 256 + (size_t)ocblk * 64) * PX;
#pragma unroll
    for (int mi = 0; mi < 4; ++mi)
#pragma unroll
        for (int ni = 0; ni < 4; ++ni) {
            int nr = ni >> 1, nc = ni & 1;
            int px = (py0 + 2 * w + nr) * 64 + pxc0 + nc * 16 + l15;
#pragma unroll
            for (int j = 0; j < 4; ++j) {
                float v = acc[mi][ni][j];
                int oc = mi * 16 + l4 * 4 + j;
                gbase[(size_t)oc * PX + px] = f2b(v);
                s1 += v;
                s2 += v * v;
            }
        }
    for (int off = 32; off; off >>= 1) {
        s1 += __shfl_down(s1, off);
        s2 += __shfl_down(s2, off);
    }
    if (l == 0) { red[w * 2] = s1; red[w * 2 + 1] = s2; }
    __syncthreads();
    if (tid == 0) {
        float a = red[0] + red[2] + red[4] + red[6];
        float q = red[1] + red[3] + red[5] + red[7];
        float* slot = gnstats + (((size_t)(s * 2 + dir) * 4 + b) * 4 + ocblk) * 2;
        atomicAdd(slot, a);
        atomicAdd(slot + 1, q);
    }
}

// K2: GN + activations + LSTM update; c stored bf16; h -> comb_t (bf16).
// grid 1024 (1-D): dirb = blockIdx&7 (XCD-local, same mapping as conv).
__global__ __launch_bounds__(256) void point_kernel2(
    const unsigned short* __restrict__ gatesb, const float* __restrict__ gnstats,
    const float* __restrict__ gnf_w, const float* __restrict__ gnf_b,
    const float* __restrict__ gnb_w, const float* __restrict__ gnb_b,
    unsigned short* __restrict__ cbuf, unsigned short* __restrict__ comb_t, int s)
{
    int dirb = blockIdx.x & 7;
    int idx = (blockIdx.x >> 3) * 256 + threadIdx.x;   // 0..32767 within dirb
    int pxl = idx & 7;
    int o8 = (idx >> 3) & 7;
    int pxh = idx >> 6;                                // 0..511
    int px = pxh * 8 + pxl;
    int dir = dirb >> 2, b = dirb & 3;

    __shared__ float gwl[256], gbl[256], mrs[8];
    int tid = threadIdx.x;
    {
        const float* __restrict__ gw = dir ? gnb_w : gnf_w;
        const float* __restrict__ gb = dir ? gnb_b : gnf_b;
        gwl[tid] = gw[tid];
        gbl[tid] = gb[tid];
    }
    if (tid < 4) {
        const float* slot = gnstats + ((size_t)(s * 2 + dir) * 4 + b) * 8 + tid * 2;
        const float invN = 1.0f / 262144.0f;
        float mean = slot[0] * invN;
        float var = slot[1] * invN - mean * mean;
        mrs[tid * 2] = mean;
        mrs[tid * 2 + 1] = rsqrtf(var + EPS);
    }
    __syncthreads();

    const unsigned short* __restrict__ gbase = gatesb + (size_t)dirb * 256 * PX + px;
    size_t cbase = ((size_t)dirb * 64 + o8 * 8) * PX + px;
    float m0 = mrs[0], r0 = mrs[1], m1 = mrs[2], r1 = mrs[3];
    float m2 = mrs[4], r2 = mrs[5], m3 = mrs[6], r3 = mrs[7];

    unsigned int packed[4];
#pragma unroll
    for (int cc = 0; cc < 8; ++cc) {
        int ch = o8 * 8 + cc;
        float g0 = b2f(gbase[(size_t)(ch) * PX]);
        float g1 = b2f(gbase[(size_t)(64 + ch) * PX]);
        float g2 = b2f(gbase[(size_t)(128 + ch) * PX]);
        float g3 = b2f(gbase[(size_t)(192 + ch) * PX]);
        float v0 = (g0 - m0) * r0 * gwl[ch] + gbl[ch];
        float v1 = (g1 - m1) * r1 * gwl[64 + ch] + gbl[64 + ch];
        float v2 = (g2 - m2) * r2 * gwl[128 + ch] + gbl[128 + ch];
        float v3 = (g3 - m3) * r3 * gwl[192 + ch] + gbl[192 + ch];
        float ig = rcpf(1.f + __expf(-v0));
        float fg = rcpf(1.f + __expf(-v1));
        float og = rcpf(1.f + __expf(-v2));
        float gg = 1.f - 2.f * rcpf(1.f + __expf(2.f * v3));
        float cold = b2f(cbuf[cbase + (size_t)cc * PX]);
        float cnew = fg * cold + ig * gg;
        float th = 1.f - 2.f * rcpf(1.f + __expf(2.f * cnew));
        float hnew = og * th;
        cbuf[cbase + (size_t)cc * PX] = f2b(cnew);
        unsigned int hb = (unsigned int)f2b(hnew);
        if (cc & 1) packed[cc >> 1] |= hb << 16;
        else        packed[cc >> 1] = hb;
    }
    int t = dir ? (15 - s) : s;
    size_t co = ((size_t)(t * 4 + b) * PX + px) * 128 + dir * 64 + o8 * 8;
    *reinterpret_cast<uint4*>(comb_t + co) =
        make_uint4(packed[0], packed[1], packed[2], packed[3]);
}

// K3: 1x1 fuse conv via MFMA; BN partial stats only.
__global__ __launch_bounds__(256) void fuse_stats2_kernel(
    const unsigned short* __restrict__ comb_t,
    const unsigned short* __restrict__ wfrag, float* __restrict__ bnparts)
{
    int n = blockIdx.x >> 4, pxb = blockIdx.x & 15;
    int tid = threadIdx.x;
    int w = tid >> 6, l = tid & 63;
    int l15 = l & 15, l4 = l >> 4;

    bf16x8 B[4][4];
#pragma unroll
    for (int ocb = 0; ocb < 4; ++ocb)
#pragma unroll
        for (int icblk = 0; icblk < 4; ++icblk)
            B[ocb][icblk] = *reinterpret_cast<const bf16x8*>(
                wfrag + (((ocb * 4 + icblk) * 64 + l) * 8));

    f32x4 acc[4][4];
#pragma unroll
    for (int i = 0; i < 4; ++i)
#pragma unroll
        for (int j = 0; j < 4; ++j)
            acc[i][j] = (f32x4){0.f, 0.f, 0.f, 0.f};

    int px0 = pxb * 256 + w * 64;
    const unsigned short* __restrict__ cb = comb_t + (size_t)n * PX * 128;
#pragma unroll
    for (int ps = 0; ps < 4; ++ps) {
        const unsigned short* ab = cb + (size_t)(px0 + ps * 16 + l15) * 128 + l4 * 8;
        bf16x8 A[4];
#pragma unroll
        for (int icblk = 0; icblk < 4; ++icblk)
            A[icblk] = *reinterpret_cast<const bf16x8*>(ab + icblk * 32);
#pragma unroll
        for (int icblk = 0; icblk < 4; ++icblk)
#pragma unroll
            for (int ocb = 0; ocb < 4; ++ocb)
                acc[ps][ocb] = __builtin_amdgcn_mfma_f32_16x16x32_bf16(
                    A[icblk], B[ocb][icblk], acc[ps][ocb], 0, 0, 0);
    }

    float s1[4] = {0, 0, 0, 0}, s2[4] = {0, 0, 0, 0};
#pragma unroll
    for (int ps = 0; ps < 4; ++ps)
#pragma unroll
        for (int ocb = 0; ocb < 4; ++ocb)
#pragma unroll
            for (int j = 0; j < 4; ++j) {
                float v = acc[ps][ocb][j];
                s1[ocb] += v;
                s2[ocb] += v * v;
            }
#pragma unroll
    for (int ocb = 0; ocb < 4; ++ocb) {
        s1[ocb] += __shfl_down(s1[ocb], 32);
        s1[ocb] += __shfl_down(s1[ocb], 16);
        s2[ocb] += __shfl_down(s2[ocb], 32);
        s2[ocb] += __shfl_down(s2[ocb], 16);
    }
    __shared__ float sred[4][4][16][2];
    if (l < 16)
#pragma unroll
        for (int ocb = 0; ocb < 4; ++ocb) {
            sred[w][ocb][l][0] = s1[ocb];
            sred[w][ocb][l][1] = s2[ocb];
        }
    __syncthreads();
    if (tid < 128) {
        int oc = tid >> 1, isq = tid & 1;
        float v = sred[0][oc >> 4][oc & 15][isq] + sred[1][oc >> 4][oc & 15][isq]
                + sred[2][oc >> 4][oc & 15][isq] + sred[3][oc >> 4][oc & 15][isq];
        atomicAdd(bnparts + (blockIdx.x & 7) * 128 + tid, v);
    }
}

// K4: recompute fuse MFMA, BN + ReLU, transposed store to out.
__global__ __launch_bounds__(256) void bn_apply2_kernel(
    const unsigned short* __restrict__ comb_t,
    const unsigned short* __restrict__ wfrag, const float* __restrict__ bnparts,
    const float* __restrict__ bn_w, const float* __restrict__ bn_b,
    float* __restrict__ out)
{
    int n = blockIdx.x >> 4, pxb = blockIdx.x & 15;
    int tid = threadIdx.x;
    int w = tid >> 6, l = tid & 63;
    int l15 = l & 15, l4 = l >> 4;

    __shared__ float sc[64], sh[64];
    if (tid < 64) {
        const float invN = 1.0f / 262144.0f;
        float S = 0.f, Q = 0.f;
#pragma unroll
        for (int p = 0; p < 8; ++p) {
            S += bnparts[p * 128 + tid * 2];
            Q += bnparts[p * 128 + tid * 2 + 1];
        }
        float mean = S * invN;
        float var = Q * invN - mean * mean;
        float scale = rsqrtf(var + EPS) * bn_w[tid];
        sc[tid] = scale;
        sh[tid] = bn_b[tid] - mean * scale;
    }

    bf16x8 B[4][4];
#pragma unroll
    for (int ocb = 0; ocb < 4; ++ocb)
#pragma unroll
        for (int icblk = 0; icblk < 4; ++icblk)
            B[ocb][icblk] = *reinterpret_cast<const bf16x8*>(
                wfrag + (((ocb * 4 + icblk) * 64 + l) * 8));
    __syncthreads();

    f32x4 acc[4][4];
#pragma unroll
    for (int i = 0; i < 4; ++i)
#pragma unroll
        for (int j = 0; j < 4; ++j)
            acc[i][j] = (f32x4){0.f, 0.f, 0.f, 0.f};

    int px0 = pxb * 256 + w * 64;
    const unsigned short* __restrict__ cb = comb_t + (size_t)n * PX * 128;
#pragma unroll
    for (int ps = 0; ps < 4; ++ps) {
        const unsigned short* ab = cb + (size_t)(px0 + ps * 16 + l15) * 128 + l4 * 8;
        bf16x8 A[4];
#pragma unroll
        for (int icblk = 0; icblk < 4; ++icblk)
            A[icblk] = *reinterpret_cast<const bf16x8*>(ab + icblk * 32);
#pragma unroll
        for (int icblk = 0; icblk < 4; ++icblk)
#pragma unroll
            for (int ocb = 0; ocb < 4; ++ocb)
                acc[ps][ocb] = __builtin_amdgcn_mfma_f32_16x16x32_bf16(
                    A[icblk], B[ocb][icblk], acc[ps][ocb], 0, 0, 0);
    }

    int t = n >> 2, bb = n & 3;
#pragma unroll
    for (int ps = 0; ps < 4; ++ps)
#pragma unroll
        for (int ocb = 0; ocb < 4; ++ocb) {
            int oc = ocb * 16 + l15;
            float scale = sc[oc], shift = sh[oc];
            float4 v;
            v.x = fmaxf(acc[ps][ocb][0] * scale + shift, 0.f);
            v.y = fmaxf(acc[ps][ocb][1] * scale + shift, 0.f);
            v.z = fmaxf(acc[ps][ocb][2] * scale + shift, 0.f);
            v.w = fmaxf(acc[ps][ocb][3] * scale + shift, 0.f);
            float* op = out + ((size_t)((bb * 16 + t) * 64 + oc)) * PX
                      + px0 + ps * 16 + l4 * 4;
            *reinterpret_cast<float4*>(op) = v;
        }
}

extern "C" void kernel_launch(void* const* d_in, const int* in_sizes, int n_in,
                              void* d_out, int out_size, void* d_ws, size_t ws_size,
                              hipStream_t stream) {
    const float* x     = (const float*)d_in[0];
    const float* Wf    = (const float*)d_in[1];
    const float* gnf_w = (const float*)d_in[2];
    const float* gnf_b = (const float*)d_in[3];
    const float* Wb    = (const float*)d_in[4];
    const float* gnb_w = (const float*)d_in[5];
    const float* gnb_b = (const float*)d_in[6];
    const float* Wfu   = (const float*)d_in[7];
    const float* bn_w  = (const float*)d_in[8];
    const float* bn_b  = (const float*)d_in[9];
    float* out = (float*)d_out;

    float* ws = (float*)d_ws;
    unsigned short* comb_t = (unsigned short*)ws;               // 16,777,216 f
    unsigned short* gatesb = (unsigned short*)(ws + 16777216);  //  4,194,304 f
    unsigned short* cbuf   = (unsigned short*)(ws + 20971520);  //  1,048,576 f
    float* gnstats = ws + 22020096;                             //      1,024 f
    float* bnparts = ws + 22021120;                             //      1,024 f
    unsigned short* W2s   = (unsigned short*)(ws + 22022144);   //    294,912 f
    unsigned short* wfrag = (unsigned short*)(ws + 22317056);   //      4,096 f
    unsigned short* xb    = (unsigned short*)(ws + 22321152);   //  8,388,608 f

    // zero c (bf16 zeros == 0x0000) + gn stats + bn partials (contiguous)
    hipMemsetAsync(cbuf, 0, (size_t)(1048576 + 2048) * 4, stream);

    pack_kernel<<<2336, 256, 0, stream>>>(Wf, Wb, Wfu, W2s, wfrag);
    xconv_kernel<<<4096, 256, 0, stream>>>(x, xb);

    for (int s = 0; s < 16; ++s) {
        conv_mfma_kernel<<<512, 256, 0, stream>>>(
            xb, comb_t, W2s, gatesb, gnstats, s);
        point_kernel2<<<1024, 256, 0, stream>>>(
            gatesb, gnstats, gnf_w, gnf_b, gnb_w, gnb_b, cbuf, comb_t, s);
    }
    fuse_stats2_kernel<<<1024, 256, 0, stream>>>(comb_t, wfrag, bnparts);
    bn_apply2_kernel<<<1024, 256, 0, stream>>>(comb_t, wfrag, bnparts, bn_w, bn_b, out);
}

// Round 19
// 556.697 us; speedup vs baseline: 2.2125x; 1.0219x over previous
//
#include <hip/hip_runtime.h>
#include <math.h>

#define PX 4096         // 64*64 spatial
#define EPS 1e-5f

typedef __attribute__((ext_vector_type(8))) __bf16 bf16x8;
typedef __attribute__((ext_vector_type(4))) float f32x4;

static __device__ __forceinline__ unsigned short f2b(float f) {
    unsigned int u = __float_as_uint(f);
    u += 0x7FFFu + ((u >> 16) & 1u);     // RTNE
    return (unsigned short)(u >> 16);
}
static __device__ __forceinline__ float b2f(unsigned short u) {
    return __uint_as_float((unsigned int)u << 16);
}
static __device__ __forceinline__ float rcpf(float x) {
    return __builtin_amdgcn_rcpf(x);
}

// ---------------------------------------------------------------------------
// ws layout (float units):
//   comb_t  bf16 [64 n][4096 px][128 ic]          16,777,216 f  @ 0
//   gatesb  bf16 [8 dirb][256 oc][4096 px]         4,194,304 f  @ 16,777,216
//   cbuf    bf16 [8 dirb][64 ch][4096]             1,048,576 f  @ 20,971,520
//   gnstat  f32  [16 s][2 dir][4 b][4 g][2]            1,024 f  @ 22,020,096
//   bnparts f32  [8 part][64 oc][2]                    1,024 f  @ 22,021,120
//   W2s     bf16 [dir][ocblk][icblk][tap][64][4][8] 294,912 f  @ 22,022,144
//   wfrag   bf16 [4 ocb][4 icblk][64 l][8 j]           4,096 f  @ 22,317,056
//   xb      bf16 [64 bt][4096 px][64 ic]            8,388,608 f @ 22,321,152
//
// R19 = R18 (569us) + in_s DOUBLE BUFFER: LDS = 36,864(Wl) + 2x21,760(in_s)
// + 32 = 80,416 B <= 81,920 (2 blocks/CU preserved). stage_write moves AFTER
// the MFMA phase (into the buffer last read 2 phases ago); the inter-barrier
// window now holds only the 9 async weight issues. Input ds_writes + next
// tile's load latency fully overlap MFMA.
// ---------------------------------------------------------------------------

// Pack conv weights (pre-swizzled LDS image) + Wfu B-fragments, one launch.
__global__ __launch_bounds__(256) void pack_kernel(
    const float* __restrict__ Wf, const float* __restrict__ Wb,
    const float* __restrict__ Wfu,
    unsigned short* __restrict__ W2s, unsigned short* __restrict__ wfrag)
{
    int idx = blockIdx.x * 256 + threadIdx.x;
    if (idx < 589824) {
        int within = idx & 2047;
        int grp = idx >> 11;
        int oc = within >> 5;
        int slot = (within >> 3) & 3;
        int j = within & 7;
        int tap = grp % 9;
        int rest = grp / 9;
        int icblk = rest & 3;
        int ocblk = (rest >> 2) & 3;
        int dir = rest >> 4;
        int c = slot ^ ((oc >> 1) & 3);
        int ic = icblk * 32 + c * 8 + j;
        int OC = ocblk * 64 + oc;
        const float* __restrict__ W = dir ? Wb : Wf;
        W2s[idx] = f2b(W[((size_t)OC * 128 + ic) * 9 + tap]);
    } else if (idx < 589824 + 8192) {
        int k = idx - 589824;
        int j = k & 7;
        int l = (k >> 3) & 63;
        int icblk = (k >> 9) & 3;
        int ocb = k >> 11;
        int oc = ocb * 16 + (l & 15);
        int ic = icblk * 32 + (l >> 4) * 8 + j;
        wfrag[k] = f2b(Wfu[oc * 128 + ic]);
    }
}

// Transpose x to px-major bf16: xb[bt][px][64 ic].
__global__ __launch_bounds__(256) void xconv_kernel(
    const float* __restrict__ x, unsigned short* __restrict__ xb)
{
    int bt = blockIdx.x >> 6;
    int px0 = (blockIdx.x & 63) * 64;
    __shared__ unsigned short sh[64 * 72];
    int tid = threadIdx.x;
    {
        int px_l = tid & 63;
        int ic4 = tid >> 6;
        const float* __restrict__ src = x + (size_t)bt * 64 * PX + px0 + px_l;
#pragma unroll
        for (int k = 0; k < 16; ++k) {
            int ic = ic4 * 16 + k;
            sh[px_l * 72 + ic] = f2b(src[(size_t)ic * PX]);
        }
    }
    __syncthreads();
    {
        int px_w = tid >> 2;
        int ch = tid & 3;
        uint4 v0 = *reinterpret_cast<const uint4*>(&sh[px_w * 72 + ch * 16]);
        uint4 v1 = *reinterpret_cast<const uint4*>(&sh[px_w * 72 + ch * 16 + 8]);
        unsigned short* dst = xb + ((size_t)bt * PX + px0 + px_w) * 64 + ch * 16;
        *reinterpret_cast<uint4*>(dst) = v0;
        *reinterpret_cast<uint4*>(dst + 8) = v1;
    }
}

// K1: implicit-GEMM conv via MFMA. Weights: async global->LDS (single Wl).
// Input: double-buffered in_s; write-after-compute schedule.
// grid 512 (1-D): dirb = blockIdx&7 (XCD-local); rest: ocblk(4) x pxt(16).
__global__ __launch_bounds__(256, 2) void conv_mfma_kernel(
    const unsigned short* __restrict__ xb, const unsigned short* __restrict__ comb_t,
    const unsigned short* __restrict__ W2s,
    unsigned short* __restrict__ gatesb, float* __restrict__ gnstats, int s)
{
    const int dirb = blockIdx.x & 7;
    const int rest = blockIdx.x >> 3;
    const int dir = dirb >> 2, b = dirb & 3;
    const int ocblk = rest >> 4;
    const int pxt = rest & 15;
    const int py0 = (pxt >> 1) * 8;
    const int pxc0 = (pxt & 1) * 32;
    const int t = dir ? (15 - s) : s;
    const int prev_t = dir ? (t + 1) : (t - 1);

    __shared__ __align__(16) unsigned short Wl[9 * 64 * 32];      // 36,864 B
    __shared__ __align__(16) unsigned short in_s[2][340 * 32];    // 43,520 B
    __shared__ float red[8];

    const int tid = threadIdx.x;
    const int w = tid >> 6;
    const int l = tid & 63;
    const int l15 = l & 15;
    const int l4 = l >> 4;
    const int wb = tid & ~63;            // wave-uniform lane-0 thread index

    const unsigned short* __restrict__ xpx = xb + (size_t)(b * 16 + t) * PX * 64;
    const unsigned short* __restrict__ hpx = comb_t
        + (size_t)(prev_t * 4 + b) * PX * 128 + dir * 64;

    // staging address precompute (per-lane, reused each phase)
    int sg_px[6];      // global pixel index, -1 if out of tile
#pragma unroll
    for (int it = 0; it < 6; ++it) {
        int idx = tid + it * 256;
        int pl = idx >> 2;
        int row = (pl * 241) >> 13;          // pl / 34
        int col = pl - row * 34;
        int gy = py0 - 1 + row;
        int gx = pxc0 - 1 + col;
        bool valid = (idx < 1360) && ((unsigned)gy < 64u) && ((unsigned)gx < 64u);
        sg_px[it] = valid ? (gy * 64 + gx) : -1;
    }

    f32x4 acc[4][4];
#pragma unroll
    for (int i = 0; i < 4; ++i)
#pragma unroll
        for (int j = 0; j < 4; ++j)
            acc[i][j] = (f32x4){0.f, 0.f, 0.f, 0.f};

    uint4 sreg[6];
    // issue input loads for icblk into sreg (no LDS write)
    auto stage_load = [&](int icblk) {
        const bool useh = icblk >= 2;
        const unsigned short* __restrict__ srcpx = useh
            ? (hpx + (icblk - 2) * 32) : (xpx + icblk * 32);
        const int rec = useh ? 128 : 64;
        const bool zero = useh && (s == 0);
        const int c = tid & 3;
#pragma unroll
        for (int it = 0; it < 6; ++it) {
            uint4 v = make_uint4(0u, 0u, 0u, 0u);
            if (sg_px[it] >= 0 && !zero)
                v = *reinterpret_cast<const uint4*>(
                    srcpx + (size_t)sg_px[it] * rec + c * 8);
            sreg[it] = v;
        }
    };
    // write sreg into in_s[buf] (swizzled)
    auto stage_write = [&](int buf) {
#pragma unroll
        for (int it = 0; it < 6; ++it) {
            int idx = tid + it * 256;
            if (idx < 1360) {
                int c = idx & 3;
                int pl = idx >> 2;
                int woff = pl * 32 + ((c ^ ((pl >> 1) & 3)) * 8);
                *reinterpret_cast<uint4*>(&in_s[buf][woff]) = sreg[it];
            }
        }
    };
    // async weight stage: 16B/lane x 9, linear LDS dest (wave-uniform base)
    auto issueW = [&](int icblk) {
        const unsigned short* __restrict__ wsrc = W2s
            + ((size_t)((dir * 4 + ocblk) * 4 + icblk) * 9) * 2048;
#pragma unroll
        for (int it = 0; it < 9; ++it) {
            __builtin_amdgcn_global_load_lds(
                (const __attribute__((address_space(1))) void*)
                    (wsrc + (size_t)(tid + it * 256) * 8),
                (__attribute__((address_space(3))) void*)
                    (&Wl[(wb + it * 256) * 8]),
                16, 0, 0);
        }
    };

    // prologue: input tile 0 staged into buf0 (visible at first syncA)
    stage_load(0);
    stage_write(0);

    for (int icblk = 0; icblk < 4; ++icblk) {
        __syncthreads();                 // A: prior compute done; buf writes visible
        issueW(icblk);
        __syncthreads();                 // B: weights drained
        if (icblk < 3) stage_load(icblk + 1);   // loads fly across MFMA
        const unsigned short* __restrict__ ib = in_s[icblk & 1];

#pragma unroll
        for (int tap = 0; tap < 9; ++tap) {
            const int dy = tap / 3, dx = tap % 3;
            bf16x8 av[4], bv[4];
#pragma unroll
            for (int mi = 0; mi < 4; ++mi) {
                int oc = mi * 16 + l15;
                int aoff = tap * 2048 + oc * 32 + ((l4 ^ ((oc >> 1) & 3)) * 8);
                av[mi] = *reinterpret_cast<const bf16x8*>(&Wl[aoff]);
            }
#pragma unroll
            for (int ni = 0; ni < 4; ++ni) {
                int nr = ni >> 1, nc = ni & 1;
                int pl = (2 * w + nr + dy) * 34 + nc * 16 + l15 + dx;
                int boff = pl * 32 + ((l4 ^ ((pl >> 1) & 3)) * 8);
                bv[ni] = *reinterpret_cast<const bf16x8*>(&ib[boff]);
            }
#pragma unroll
            for (int mi = 0; mi < 4; ++mi)
#pragma unroll
                for (int ni = 0; ni < 4; ++ni)
                    acc[mi][ni] = __builtin_amdgcn_mfma_f32_16x16x32_bf16(
                        av[mi], bv[ni], acc[mi][ni], 0, 0, 0);
        }

        // write next tile into the spare buffer (last read 2 phases ago)
        if (icblk < 3) stage_write((icblk + 1) & 1);
    }

    // epilogue: write gates (bf16) + GN partial stats (fp32 from acc)
    float s1 = 0.f, s2 = 0.f;
    unsigned short* __restrict__ gbase = gatesb
        + ((size_t)dirb * 256 + (size_t)ocblk * 64) * PX;
#pragma unroll
    for (int mi = 0; mi < 4; ++mi)
#pragma unroll
        for (int ni = 0; ni < 4; ++ni) {
            int nr = ni >> 1, nc = ni & 1;
            int px = (py0 + 2 * w + nr) * 64 + pxc0 + nc * 16 + l15;
#pragma unroll
            for (int j = 0; j < 4; ++j) {
                float v = acc[mi][ni][j];
                int oc = mi * 16 + l4 * 4 + j;
                gbase[(size_t)oc * PX + px] = f2b(v);
                s1 += v;
                s2 += v * v;
            }
        }
    for (int off = 32; off; off >>= 1) {
        s1 += __shfl_down(s1, off);
        s2 += __shfl_down(s2, off);
    }
    if (l == 0) { red[w * 2] = s1; red[w * 2 + 1] = s2; }
    __syncthreads();
    if (tid == 0) {
        float a = red[0] + red[2] + red[4] + red[6];
        float q = red[1] + red[3] + red[5] + red[7];
        float* slot = gnstats + (((size_t)(s * 2 + dir) * 4 + b) * 4 + ocblk) * 2;
        atomicAdd(slot, a);
        atomicAdd(slot + 1, q);
    }
}

// K2: GN + activations + LSTM update; c stored bf16; h -> comb_t (bf16).
// grid 1024 (1-D): dirb = blockIdx&7 (XCD-local, same mapping as conv).
__global__ __launch_bounds__(256) void point_kernel2(
    const unsigned short* __restrict__ gatesb, const float* __restrict__ gnstats,
    const float* __restrict__ gnf_w, const float* __restrict__ gnf_b,
    const float* __restrict__ gnb_w, const float* __restrict__ gnb_b,
    unsigned short* __restrict__ cbuf, unsigned short* __restrict__ comb_t, int s)
{
    int dirb = blockIdx.x & 7;
    int idx = (blockIdx.x >> 3) * 256 + threadIdx.x;   // 0..32767 within dirb
    int pxl = idx & 7;
    int o8 = (idx >> 3) & 7;
    int pxh = idx >> 6;                                // 0..511
    int px = pxh * 8 + pxl;
    int dir = dirb >> 2, b = dirb & 3;

    __shared__ float gwl[256], gbl[256], mrs[8];
    int tid = threadIdx.x;
    {
        const float* __restrict__ gw = dir ? gnb_w : gnf_w;
        const float* __restrict__ gb = dir ? gnb_b : gnf_b;
        gwl[tid] = gw[tid];
        gbl[tid] = gb[tid];
    }
    if (tid < 4) {
        const float* slot = gnstats + ((size_t)(s * 2 + dir) * 4 + b) * 8 + tid * 2;
        const float invN = 1.0f / 262144.0f;
        float mean = slot[0] * invN;
        float var = slot[1] * invN - mean * mean;
        mrs[tid * 2] = mean;
        mrs[tid * 2 + 1] = rsqrtf(var + EPS);
    }
    __syncthreads();

    const unsigned short* __restrict__ gbase = gatesb + (size_t)dirb * 256 * PX + px;
    size_t cbase = ((size_t)dirb * 64 + o8 * 8) * PX + px;
    float m0 = mrs[0], r0 = mrs[1], m1 = mrs[2], r1 = mrs[3];
    float m2 = mrs[4], r2 = mrs[5], m3 = mrs[6], r3 = mrs[7];

    unsigned int packed[4];
#pragma unroll
    for (int cc = 0; cc < 8; ++cc) {
        int ch = o8 * 8 + cc;
        float g0 = b2f(gbase[(size_t)(ch) * PX]);
        float g1 = b2f(gbase[(size_t)(64 + ch) * PX]);
        float g2 = b2f(gbase[(size_t)(128 + ch) * PX]);
        float g3 = b2f(gbase[(size_t)(192 + ch) * PX]);
        float v0 = (g0 - m0) * r0 * gwl[ch] + gbl[ch];
        float v1 = (g1 - m1) * r1 * gwl[64 + ch] + gbl[64 + ch];
        float v2 = (g2 - m2) * r2 * gwl[128 + ch] + gbl[128 + ch];
        float v3 = (g3 - m3) * r3 * gwl[192 + ch] + gbl[192 + ch];
        float ig = rcpf(1.f + __expf(-v0));
        float fg = rcpf(1.f + __expf(-v1));
        float og = rcpf(1.f + __expf(-v2));
        float gg = 1.f - 2.f * rcpf(1.f + __expf(2.f * v3));
        float cold = b2f(cbuf[cbase + (size_t)cc * PX]);
        float cnew = fg * cold + ig * gg;
        float th = 1.f - 2.f * rcpf(1.f + __expf(2.f * cnew));
        float hnew = og * th;
        cbuf[cbase + (size_t)cc * PX] = f2b(cnew);
        unsigned int hb = (unsigned int)f2b(hnew);
        if (cc & 1) packed[cc >> 1] |= hb << 16;
        else        packed[cc >> 1] = hb;
    }
    int t = dir ? (15 - s) : s;
    size_t co = ((size_t)(t * 4 + b) * PX + px) * 128 + dir * 64 + o8 * 8;
    *reinterpret_cast<uint4*>(comb_t + co) =
        make_uint4(packed[0], packed[1], packed[2], packed[3]);
}

// K3: 1x1 fuse conv via MFMA; BN partial stats only.
__global__ __launch_bounds__(256) void fuse_stats2_kernel(
    const unsigned short* __restrict__ comb_t,
    const unsigned short* __restrict__ wfrag, float* __restrict__ bnparts)
{
    int n = blockIdx.x >> 4, pxb = blockIdx.x & 15;
    int tid = threadIdx.x;
    int w = tid >> 6, l = tid & 63;
    int l15 = l & 15, l4 = l >> 4;

    bf16x8 B[4][4];
#pragma unroll
    for (int ocb = 0; ocb < 4; ++ocb)
#pragma unroll
        for (int icblk = 0; icblk < 4; ++icblk)
            B[ocb][icblk] = *reinterpret_cast<const bf16x8*>(
                wfrag + (((ocb * 4 + icblk) * 64 + l) * 8));

    f32x4 acc[4][4];
#pragma unroll
    for (int i = 0; i < 4; ++i)
#pragma unroll
        for (int j = 0; j < 4; ++j)
            acc[i][j] = (f32x4){0.f, 0.f, 0.f, 0.f};

    int px0 = pxb * 256 + w * 64;
    const unsigned short* __restrict__ cb = comb_t + (size_t)n * PX * 128;
#pragma unroll
    for (int ps = 0; ps < 4; ++ps) {
        const unsigned short* ab = cb + (size_t)(px0 + ps * 16 + l15) * 128 + l4 * 8;
        bf16x8 A[4];
#pragma unroll
        for (int icblk = 0; icblk < 4; ++icblk)
            A[icblk] = *reinterpret_cast<const bf16x8*>(ab + icblk * 32);
#pragma unroll
        for (int icblk = 0; icblk < 4; ++icblk)
#pragma unroll
            for (int ocb = 0; ocb < 4; ++ocb)
                acc[ps][ocb] = __builtin_amdgcn_mfma_f32_16x16x32_bf16(
                    A[icblk], B[ocb][icblk], acc[ps][ocb], 0, 0, 0);
    }

    float s1[4] = {0, 0, 0, 0}, s2[4] = {0, 0, 0, 0};
#pragma unroll
    for (int ps = 0; ps < 4; ++ps)
#pragma unroll
        for (int ocb = 0; ocb < 4; ++ocb)
#pragma unroll
            for (int j = 0; j < 4; ++j) {
                float v = acc[ps][ocb][j];
                s1[ocb] += v;
                s2[ocb] += v * v;
            }
#pragma unroll
    for (int ocb = 0; ocb < 4; ++ocb) {
        s1[ocb] += __shfl_down(s1[ocb], 32);
        s1[ocb] += __shfl_down(s1[ocb], 16);
        s2[ocb] += __shfl_down(s2[ocb], 32);
        s2[ocb] += __shfl_down(s2[ocb], 16);
    }
    __shared__ float sred[4][4][16][2];
    if (l < 16)
#pragma unroll
        for (int ocb = 0; ocb < 4; ++ocb) {
            sred[w][ocb][l][0] = s1[ocb];
            sred[w][ocb][l][1] = s2[ocb];
        }
    __syncthreads();
    if (tid < 128) {
        int oc = tid >> 1, isq = tid & 1;
        float v = sred[0][oc >> 4][oc & 15][isq] + sred[1][oc >> 4][oc & 15][isq]
                + sred[2][oc >> 4][oc & 15][isq] + sred[3][oc >> 4][oc & 15][isq];
        atomicAdd(bnparts + (blockIdx.x & 7) * 128 + tid, v);
    }
}

// K4: recompute fuse MFMA, BN + ReLU, transposed store to out.
__global__ __launch_bounds__(256) void bn_apply2_kernel(
    const unsigned short* __restrict__ comb_t,
    const unsigned short* __restrict__ wfrag, const float* __restrict__ bnparts,
    const float* __restrict__ bn_w, const float* __restrict__ bn_b,
    float* __restrict__ out)
{
    int n = blockIdx.x >> 4, pxb = blockIdx.x & 15;
    int tid = threadIdx.x;
    int w = tid >> 6, l = tid & 63;
    int l15 = l & 15, l4 = l >> 4;

    __shared__ float sc[64], sh[64];
    if (tid < 64) {
        const float invN = 1.0f / 262144.0f;
        float S = 0.f, Q = 0.f;
#pragma unroll
        for (int p = 0; p < 8; ++p) {
            S += bnparts[p * 128 + tid * 2];
            Q += bnparts[p * 128 + tid * 2 + 1];
        }
        float mean = S * invN;
        float var = Q * invN - mean * mean;
        float scale = rsqrtf(var + EPS) * bn_w[tid];
        sc[tid] = scale;
        sh[tid] = bn_b[tid] - mean * scale;
    }

    bf16x8 B[4][4];
#pragma unroll
    for (int ocb = 0; ocb < 4; ++ocb)
#pragma unroll
        for (int icblk = 0; icblk < 4; ++icblk)
            B[ocb][icblk] = *reinterpret_cast<const bf16x8*>(
                wfrag + (((ocb * 4 + icblk) * 64 + l) * 8));
    __syncthreads();

    f32x4 acc[4][4];
#pragma unroll
    for (int i = 0; i < 4; ++i)
#pragma unroll
        for (int j = 0; j < 4; ++j)
            acc[i][j] = (f32x4){0.f, 0.f, 0.f, 0.f};

    int px0 = pxb * 256 + w * 64;
    const unsigned short* __restrict__ cb = comb_t + (size_t)n * PX * 128;
#pragma unroll
    for (int ps = 0; ps < 4; ++ps) {
        const unsigned short* ab = cb + (size_t)(px0 + ps * 16 + l15) * 128 + l4 * 8;
        bf16x8 A[4];
#pragma unroll
        for (int icblk = 0; icblk < 4; ++icblk)
            A[icblk] = *reinterpret_cast<const bf16x8*>(ab + icblk * 32);
#pragma unroll
        for (int icblk = 0; icblk < 4; ++icblk)
#pragma unroll
            for (int ocb = 0; ocb < 4; ++ocb)
                acc[ps][ocb] = __builtin_amdgcn_mfma_f32_16x16x32_bf16(
                    A[icblk], B[ocb][icblk], acc[ps][ocb], 0, 0, 0);
    }

    int t = n >> 2, bb = n & 3;
#pragma unroll
    for (int ps = 0; ps < 4; ++ps)
#pragma unroll
        for (int ocb = 0; ocb < 4; ++ocb) {
            int oc = ocb * 16 + l15;
            float scale = sc[oc], shift = sh[oc];
            float4 v;
            v.x = fmaxf(acc[ps][ocb][0] * scale + shift, 0.f);
            v.y = fmaxf(acc[ps][ocb][1] * scale + shift, 0.f);
            v.z = fmaxf(acc[ps][ocb][2] * scale + shift, 0.f);
            v.w = fmaxf(acc[ps][ocb][3] * scale + shift, 0.f);
            float* op = out + ((size_t)((bb * 16 + t) * 64 + oc)) * PX
                      + px0 + ps * 16 + l4 * 4;
            *reinterpret_cast<float4*>(op) = v;
        }
}

extern "C" void kernel_launch(void* const* d_in, const int* in_sizes, int n_in,
                              void* d_out, int out_size, void* d_ws, size_t ws_size,
                              hipStream_t stream) {
    const float* x     = (const float*)d_in[0];
    const float* Wf    = (const float*)d_in[1];
    const float* gnf_w = (const float*)d_in[2];
    const float* gnf_b = (const float*)d_in[3];
    const float* Wb    = (const float*)d_in[4];
    const float* gnb_w = (const float*)d_in[5];
    const float* gnb_b = (const float*)d_in[6];
    const float* Wfu   = (const float*)d_in[7];
    const float* bn_w  = (const float*)d_in[8];
    const float* bn_b  = (const float*)d_in[9];
    float* out = (float*)d_out;

    float* ws = (float*)d_ws;
    unsigned short* comb_t = (unsigned short*)ws;               // 16,777,216 f
    unsigned short* gatesb = (unsigned short*)(ws + 16777216);  //  4,194,304 f
    unsigned short* cbuf   = (unsigned short*)(ws + 20971520);  //  1,048,576 f
    float* gnstats = ws + 22020096;                             //      1,024 f
    float* bnparts = ws + 22021120;                             //      1,024 f
    unsigned short* W2s   = (unsigned short*)(ws + 22022144);   //    294,912 f
    unsigned short* wfrag = (unsigned short*)(ws + 22317056);   //      4,096 f
    unsigned short* xb    = (unsigned short*)(ws + 22321152);   //  8,388,608 f

    // zero c (bf16 zeros == 0x0000) + gn stats + bn partials (contiguous)
    hipMemsetAsync(cbuf, 0, (size_t)(1048576 + 2048) * 4, stream);

    pack_kernel<<<2336, 256, 0, stream>>>(Wf, Wb, Wfu, W2s, wfrag);
    xconv_kernel<<<4096, 256, 0, stream>>>(x, xb);

    for (int s = 0; s < 16; ++s) {
        conv_mfma_kernel<<<512, 256, 0, stream>>>(
            xb, comb_t, W2s, gatesb, gnstats, s);
        point_kernel2<<<1024, 256, 0, stream>>>(
            gatesb, gnstats, gnf_w, gnf_b, gnb_w, gnb_b, cbuf, comb_t, s);
    }
    fuse_stats2_kernel<<<1024, 256, 0, stream>>>(comb_t, wfrag, bnparts);
    bn_apply2_kernel<<<1024, 256, 0, stream>>>(comb_t, wfrag, bnparts, bn_w, bn_b, out);
}